// Round 1
// baseline (28196.820 us; speedup 1.0000x reference)
//
#include <hip/hip_runtime.h>
#include <hip/hip_bf16.h>

// Problem constants (validated against in_sizes at launch)
#define NF   128   // in_channels
#define DD1  256   // dim_1
#define DD2  64    // dim_1/4
#define HATT 128   // attention hidden

static inline int cdiv(int a, int b) { return (a + b - 1) / b; }

// ---------------------------------------------------------------------------
// degree counting + inversion
// ---------------------------------------------------------------------------
__global__ __launch_bounds__(256) void count_deg(const int* __restrict__ nidx,
                                                 const int* __restrict__ eidx,
                                                 float* __restrict__ degn,
                                                 float* __restrict__ dege, int E) {
    int t = blockIdx.x * 256 + threadIdx.x;
    if (t < E) {
        atomicAdd(&degn[nidx[t]], 1.0f);
        atomicAdd(&dege[eidx[t]], 1.0f);
    }
}

__global__ __launch_bounds__(256) void invert_deg(float* __restrict__ d, int n) {
    int t = blockIdx.x * 256 + threadIdx.x;
    if (t < n) {
        float v = d[t];
        d[t] = v > 0.f ? 1.0f / v : 0.f;
    }
}

// ---------------------------------------------------------------------------
// f32 GEMM: C[M,Nc] = f(A)[M,K] @ B[K,Nc]
// optional pre-transform on A: a_eff = relu(pre_scale[row]*a + pre_bias[col])
// 64x64 tile, BK=16, 256 threads, 4x4 micro-tile per thread.
// ---------------------------------------------------------------------------
__global__ __launch_bounds__(256) void gemm_f32(const float* __restrict__ A,
                                                const float* __restrict__ B,
                                                float* __restrict__ C,
                                                int M, int K, int Nc,
                                                const float* __restrict__ pre_scale,
                                                const float* __restrict__ pre_bias) {
    __shared__ float As[16][68];   // [k][m], padded stride 68 (bank-stagger)
    __shared__ float Bs[16][64];   // [k][n]
    const int tid = threadIdx.x;
    const int bm = blockIdx.y * 64;
    const int bn = blockIdx.x * 64;
    const int tm = (tid >> 4) << 2;
    const int tn = (tid & 15) << 2;
    const int arow = tid >> 2;          // 0..63
    const int akq  = (tid & 3) << 2;    // 0,4,8,12
    const int brow = tid >> 4;          // 0..15
    const int bnq  = (tid & 15) << 2;   // 0..60

    float acc[4][4] = {{0.f}};

    for (int k0 = 0; k0 < K; k0 += 16) {
        float4 av = make_float4(0.f, 0.f, 0.f, 0.f);
        const int gr = bm + arow;
        if (gr < M) {
            av = *(const float4*)&A[(size_t)gr * K + k0 + akq];
            if (pre_scale) {
                const float s = pre_scale[gr];
                av.x = fmaxf(fmaf(av.x, s, pre_bias[k0 + akq + 0]), 0.f);
                av.y = fmaxf(fmaf(av.y, s, pre_bias[k0 + akq + 1]), 0.f);
                av.z = fmaxf(fmaf(av.z, s, pre_bias[k0 + akq + 2]), 0.f);
                av.w = fmaxf(fmaf(av.w, s, pre_bias[k0 + akq + 3]), 0.f);
            }
        }
        const float4 bv = *(const float4*)&B[(size_t)(k0 + brow) * Nc + bn + bnq];
        As[akq + 0][arow] = av.x;
        As[akq + 1][arow] = av.y;
        As[akq + 2][arow] = av.z;
        As[akq + 3][arow] = av.w;
        *(float4*)&Bs[brow][bnq] = bv;
        __syncthreads();
#pragma unroll
        for (int kk = 0; kk < 16; kk++) {
            const float a0 = As[kk][tm + 0];
            const float a1 = As[kk][tm + 1];
            const float a2 = As[kk][tm + 2];
            const float a3 = As[kk][tm + 3];
            const float4 b = *(const float4*)&Bs[kk][tn];
            acc[0][0] = fmaf(a0, b.x, acc[0][0]);
            acc[0][1] = fmaf(a0, b.y, acc[0][1]);
            acc[0][2] = fmaf(a0, b.z, acc[0][2]);
            acc[0][3] = fmaf(a0, b.w, acc[0][3]);
            acc[1][0] = fmaf(a1, b.x, acc[1][0]);
            acc[1][1] = fmaf(a1, b.y, acc[1][1]);
            acc[1][2] = fmaf(a1, b.z, acc[1][2]);
            acc[1][3] = fmaf(a1, b.w, acc[1][3]);
            acc[2][0] = fmaf(a2, b.x, acc[2][0]);
            acc[2][1] = fmaf(a2, b.y, acc[2][1]);
            acc[2][2] = fmaf(a2, b.z, acc[2][2]);
            acc[2][3] = fmaf(a2, b.w, acc[2][3]);
            acc[3][0] = fmaf(a3, b.x, acc[3][0]);
            acc[3][1] = fmaf(a3, b.y, acc[3][1]);
            acc[3][2] = fmaf(a3, b.z, acc[3][2]);
            acc[3][3] = fmaf(a3, b.w, acc[3][3]);
        }
        __syncthreads();
    }
#pragma unroll
    for (int r = 0; r < 4; r++) {
        const int gr = bm + tm + r;
        if (gr < M)
            *(float4*)&C[(size_t)gr * Nc + bn + tn] =
                make_float4(acc[r][0], acc[r][1], acc[r][2], acc[r][3]);
    }
}

// ---------------------------------------------------------------------------
// edge scatter: dst[idx_dst[e]] += (scale ? scale[idx_src[e]] : 1) * src[idx_src[e]]
// D floats/row, D/4 lanes per row with float4.
// ---------------------------------------------------------------------------
template <int D>
__global__ __launch_bounds__(256) void scatter_rows(const float* __restrict__ src,
                                                    const int* __restrict__ idx_src,
                                                    const int* __restrict__ idx_dst,
                                                    const float* __restrict__ scale,
                                                    float* __restrict__ dst, int E) {
    constexpr int TPR = D / 4;
    constexpr int RPB = 256 / TPR;
    const int r = blockIdx.x * RPB + threadIdx.x / TPR;
    const int c = (threadIdx.x % TPR) << 2;
    if (r >= E) return;
    const int sr = idx_src[r];
    const int dr = idx_dst[r];
    float4 v = *(const float4*)&src[(size_t)sr * D + c];
    if (scale) {
        const float s = scale[sr];
        v.x *= s; v.y *= s; v.z *= s; v.w *= s;
    }
    float* dp = &dst[(size_t)dr * D + c];
    atomicAdd(dp + 0, v.x);
    atomicAdd(dp + 1, v.y);
    atomicAdd(dp + 2, v.z);
    atomicAdd(dp + 3, v.w);
}

// ---------------------------------------------------------------------------
// h2 = relu(d_inv[row]*raw + b2[col]) over [Nn, 64]
// ---------------------------------------------------------------------------
__global__ __launch_bounds__(256) void finalize_h2(const float* __restrict__ raw,
                                                   const float* __restrict__ d_inv,
                                                   const float* __restrict__ b2,
                                                   float* __restrict__ out, int Nn) {
    const int t = blockIdx.x * 256 + threadIdx.x;  // over Nn*16 float4s
    if (t >= Nn * 16) return;
    const int r = t >> 4;
    const int c = (t & 15) << 2;
    const float s = d_inv[r];
    const float4 v = *(const float4*)&raw[(size_t)t * 4];
    float4 o;
    o.x = fmaxf(fmaf(v.x, s, b2[c + 0]), 0.f);
    o.y = fmaxf(fmaf(v.y, s, b2[c + 1]), 0.f);
    o.z = fmaxf(fmaf(v.z, s, b2[c + 2]), 0.f);
    o.w = fmaxf(fmaf(v.w, s, b2[c + 3]), 0.f);
    *(float4*)&out[(size_t)t * 4] = o;
}

// ---------------------------------------------------------------------------
// hyperedge embedding: out[m] = sum_l (hnode[m,l]>0 ? emb[hnode[m,l]-1] : 0) / (hlen[m]+eps)
// 16 lanes per row (float4 each), 16 rows per block.
// ---------------------------------------------------------------------------
__global__ __launch_bounds__(256) void hye_emb_kernel(const float* __restrict__ emb,
                                                      const int* __restrict__ hnode,
                                                      const float* __restrict__ hlen,
                                                      float* __restrict__ out, int Nn) {
    const int r = blockIdx.x * 16 + (threadIdx.x >> 4);
    const int c = (threadIdx.x & 15) << 2;
    if (r >= Nn) return;
    const int* hp = &hnode[(size_t)r * 16];
    float4 acc = make_float4(0.f, 0.f, 0.f, 0.f);
#pragma unroll
    for (int l = 0; l < 16; l++) {
        const int idx = hp[l];
        if (idx > 0) {
            const float4 v = *(const float4*)&emb[(size_t)(idx - 1) * 64 + c];
            acc.x += v.x; acc.y += v.y; acc.z += v.z; acc.w += v.w;
        }
    }
    const float inv = 1.0f / (hlen[r] + 1e-15f);
    acc.x *= inv; acc.y *= inv; acc.z *= inv; acc.w *= inv;
    *(float4*)&out[(size_t)r * 64 + c] = acc;
}

// ---------------------------------------------------------------------------
// attention scores: acc[j] += sum_i tanh(z_j[i] @ W1 + b1) @ W2   (j = 0..3)
// block = 256 threads = 64 nodes x 4 components. W1 (64x128) staged in LDS.
// ---------------------------------------------------------------------------
__global__ __launch_bounds__(256) void attn_score(const float* __restrict__ z0,
                                                  const float* __restrict__ z1,
                                                  const float* __restrict__ z2,
                                                  const float* __restrict__ z3,
                                                  const float* __restrict__ W1,
                                                  const float* __restrict__ b1v,
                                                  const float* __restrict__ W2v,
                                                  float* __restrict__ accp, int Nn) {
    __shared__ float W1s[64 * 128];
    __shared__ float b1s[128];
    __shared__ float W2s[128];
    const int tid = threadIdx.x;
    for (int t = tid; t < 64 * 128; t += 256) W1s[t] = W1[t];
    if (tid < 128) { b1s[tid] = b1v[tid]; W2s[tid] = W2v[tid]; }
    __syncthreads();

    const int i = blockIdx.x * 64 + (tid >> 2);
    const int j = tid & 3;
    const float* zp = (j == 0) ? z0 : (j == 1) ? z1 : (j == 2) ? z2 : z3;

    float val = 0.f;
    if (i < Nn) {
        float zr[64];
        const float4* zrow = (const float4*)(zp + (size_t)i * 64);
#pragma unroll
        for (int q = 0; q < 16; q++) {
            const float4 v = zrow[q];
            zr[4 * q + 0] = v.x; zr[4 * q + 1] = v.y;
            zr[4 * q + 2] = v.z; zr[4 * q + 3] = v.w;
        }
        for (int h = 0; h < HATT; h += 4) {
            float s0 = b1s[h + 0], s1 = b1s[h + 1], s2 = b1s[h + 2], s3 = b1s[h + 3];
#pragma unroll
            for (int k = 0; k < 64; k++) {
                const float4 wv = *(const float4*)&W1s[k * 128 + h];
                const float zk = zr[k];
                s0 = fmaf(zk, wv.x, s0);
                s1 = fmaf(zk, wv.y, s1);
                s2 = fmaf(zk, wv.z, s2);
                s3 = fmaf(zk, wv.w, s3);
            }
            val += tanhf(s0) * W2s[h + 0] + tanhf(s1) * W2s[h + 1] +
                   tanhf(s2) * W2s[h + 2] + tanhf(s3) * W2s[h + 3];
        }
    }
    // reduce within wave over lanes with the same j (stride-4 groups)
#pragma unroll
    for (int off = 32; off >= 4; off >>= 1) val += __shfl_down(val, off, 64);
    if ((tid & 63) < 4) atomicAdd(&accp[j], val);
}

// beta = softmax(acc/N) for both heads (acc[0..3] head c, acc[4..7] head m)
__global__ void softmax_beta(const float* __restrict__ acc, float* __restrict__ beta,
                             float invN) {
    const int t = threadIdx.x;
    if (t < 2) {
        const float* a = acc + 4 * t;
        float* b = beta + 4 * t;
        float w[4], m = -1e30f;
#pragma unroll
        for (int i = 0; i < 4; i++) { w[i] = a[i] * invN; m = fmaxf(m, w[i]); }
        float s = 0.f;
#pragma unroll
        for (int i = 0; i < 4; i++) { w[i] = expf(w[i] - m); s += w[i]; }
#pragma unroll
        for (int i = 0; i < 4; i++) b[i] = w[i] / s;
    }
}

// out[i] = sum_j beta[j] * z_j[i]
__global__ __launch_bounds__(256) void weighted_sum(const float* __restrict__ z0,
                                                    const float* __restrict__ z1,
                                                    const float* __restrict__ z2,
                                                    const float* __restrict__ z3,
                                                    const float* __restrict__ beta,
                                                    float* __restrict__ out, int Nn) {
    const int t = blockIdx.x * 256 + threadIdx.x;  // over Nn*16 float4s
    if (t >= Nn * 16) return;
    const float b0 = beta[0], b1 = beta[1], b2 = beta[2], b3 = beta[3];
    const float4 v0 = *(const float4*)&z0[(size_t)t * 4];
    const float4 v1 = *(const float4*)&z1[(size_t)t * 4];
    const float4 v2 = *(const float4*)&z2[(size_t)t * 4];
    const float4 v3 = *(const float4*)&z3[(size_t)t * 4];
    float4 o;
    o.x = b0 * v0.x + b1 * v1.x + b2 * v2.x + b3 * v3.x;
    o.y = b0 * v0.y + b1 * v1.y + b2 * v2.y + b3 * v3.y;
    o.z = b0 * v0.z + b1 * v1.z + b2 * v2.z + b3 * v3.z;
    o.w = b0 * v0.w + b1 * v1.w + b2 * v2.w + b3 * v3.w;
    *(float4*)&out[(size_t)t * 4] = o;
}

// ---------------------------------------------------------------------------
extern "C" void kernel_launch(void* const* d_in, const int* in_sizes, int n_in,
                              void* d_out, int out_size, void* d_ws, size_t ws_size,
                              hipStream_t stream) {
    const int Nn = in_sizes[0] / NF;   // 50000
    const int E  = in_sizes[1] / 2;    // 800000

    const float* x[4];
    const int*   ei[4];
    const int*   hnode[4];
    const float* hlen[4];
    for (int g = 0; g < 4; g++) {
        x[g]     = (const float*)d_in[4 * g + 0];
        ei[g]    = (const int*)d_in[4 * g + 1];
        hnode[g] = (const int*)d_in[4 * g + 2];
        hlen[g]  = (const float*)d_in[4 * g + 3];
    }
    const float* W1   = (const float*)d_in[16];
    const float* b1   = (const float*)d_in[17];
    const float* W2   = (const float*)d_in[18];
    const float* b2   = (const float*)d_in[19];
    const float* acW1 = (const float*)d_in[20];
    const float* acb1 = (const float*)d_in[21];
    const float* acW2 = (const float*)d_in[22];
    const float* amW1 = (const float*)d_in[23];
    const float* amb1 = (const float*)d_in[24];
    const float* amW2 = (const float*)d_in[25];

    // workspace layout (floats)
    float* ws = (float*)d_ws;
    size_t o = 0;
    float* bufA = ws + o; o += (size_t)Nn * DD1;   // xlin / x2lin
    float* bufB = ws + o; o += (size_t)Nn * DD1;   // e*_raw
    float* bufC = ws + o; o += (size_t)Nn * DD1;   // h*_raw
    float* degn = ws + o; o += Nn;                 // -> d_inv
    float* dege = ws + o; o += Nn;                 // -> b_inv (contiguous w/ degn)
    float* h2[4];
    float* hemb[4];
    for (int g = 0; g < 4; g++) { h2[g]   = ws + o; o += (size_t)Nn * DD2; }
    for (int g = 0; g < 4; g++) { hemb[g] = ws + o; o += (size_t)Nn * DD2; }
    float* accw = ws + o; o += 8;
    float* beta = ws + o; o += 8;

    for (int g = 0; g < 4; g++) {
        const int* nidx = ei[g];
        const int* eidx = ei[g] + E;

        hipMemsetAsync(degn, 0, (size_t)2 * Nn * sizeof(float), stream);
        count_deg<<<cdiv(E, 256), 256, 0, stream>>>(nidx, eidx, degn, dege, E);
        invert_deg<<<cdiv(2 * Nn, 256), 256, 0, stream>>>(degn, 2 * Nn);

        // xlin = x @ W1   [Nn,128]@[128,256]
        gemm_f32<<<dim3(DD1 / 64, cdiv(Nn, 64)), 256, 0, stream>>>(
            x[g], W1, bufA, Nn, NF, DD1, nullptr, nullptr);

        // e1_raw[eidx] += xlin[nidx]
        hipMemsetAsync(bufB, 0, (size_t)Nn * DD1 * sizeof(float), stream);
        scatter_rows<DD1><<<cdiv(E, 4), 256, 0, stream>>>(bufA, nidx, eidx, nullptr, bufB, E);
        // h1_raw[nidx] += b_inv[eidx] * e1_raw[eidx]
        hipMemsetAsync(bufC, 0, (size_t)Nn * DD1 * sizeof(float), stream);
        scatter_rows<DD1><<<cdiv(E, 4), 256, 0, stream>>>(bufB, eidx, nidx, dege, bufC, E);

        // x2lin = relu(d_inv*h1_raw + b1) @ W2   [Nn,256]@[256,64]
        gemm_f32<<<dim3(1, cdiv(Nn, 64)), 256, 0, stream>>>(
            bufC, W2, bufA, Nn, DD1, DD2, degn, b1);

        // e2_raw[eidx] += x2lin[nidx]
        hipMemsetAsync(bufB, 0, (size_t)Nn * DD2 * sizeof(float), stream);
        scatter_rows<DD2><<<cdiv(E, 16), 256, 0, stream>>>(bufA, nidx, eidx, nullptr, bufB, E);
        // h2_raw[nidx] += b_inv[eidx] * e2_raw[eidx]
        hipMemsetAsync(bufC, 0, (size_t)Nn * DD2 * sizeof(float), stream);
        scatter_rows<DD2><<<cdiv(E, 16), 256, 0, stream>>>(bufB, eidx, nidx, dege, bufC, E);

        // h2 = relu(d_inv*h2_raw + b2)
        finalize_h2<<<cdiv(Nn * 16, 256), 256, 0, stream>>>(bufC, degn, b2, h2[g], Nn);

        // hyperedge embedding
        hye_emb_kernel<<<cdiv(Nn, 16), 256, 0, stream>>>(h2[g], hnode[g], hlen[g], hemb[g], Nn);
    }

    // fusion attention
    hipMemsetAsync(accw, 0, 8 * sizeof(float), stream);
    // head c: (x1_mc, x2_cm, x1_cc, x2_cc) = (h2[1], hemb[0], h2[2], hemb[2])
    attn_score<<<cdiv(Nn, 64), 256, 0, stream>>>(h2[1], hemb[0], h2[2], hemb[2],
                                                 acW1, acb1, acW2, accw + 0, Nn);
    // head m: (x1_cm, x2_mc, x1_mm, x2_mm) = (h2[0], hemb[1], h2[3], hemb[3])
    attn_score<<<cdiv(Nn, 64), 256, 0, stream>>>(h2[0], hemb[1], h2[3], hemb[3],
                                                 amW1, amb1, amW2, accw + 4, Nn);
    softmax_beta<<<1, 64, 0, stream>>>(accw, beta, 1.0f / (float)Nn);

    float* out = (float*)d_out;
    weighted_sum<<<cdiv(Nn * 16, 256), 256, 0, stream>>>(h2[1], hemb[0], h2[2], hemb[2],
                                                         beta + 0, out, Nn);
    weighted_sum<<<cdiv(Nn * 16, 256), 256, 0, stream>>>(h2[0], hemb[1], h2[3], hemb[3],
                                                         beta + 4, out + (size_t)Nn * DD2, Nn);
}

// Round 2
// 3103.178 us; speedup vs baseline: 9.0864x; 9.0864x over previous
//
#include <hip/hip_runtime.h>
#include <hip/hip_bf16.h>

// Problem constants
#define NF   128   // in_channels
#define DD1  256   // dim_1
#define DD2  64    // dim_1/4
#define HATT 128   // attention hidden

static inline int cdiv(int a, int b) { return (a + b - 1) / b; }

// ---------------------------------------------------------------------------
// CSR build: degree count (int), hierarchical exclusive scan, bucket fill.
// deg/off/cursor are over the concatenated [node | edge] index space (2N).
// srcidx[slot] holds the SOURCE row for that destination slot:
//   CSR_n (rows 0..N-1):   sources are edge rows (eidx)
//   CSR_e (rows N..2N-1):  sources are node rows (nidx)
// ---------------------------------------------------------------------------
__global__ __launch_bounds__(256) void count_deg_int(const int* __restrict__ nidx,
                                                     const int* __restrict__ eidx,
                                                     int* __restrict__ deg,
                                                     int N, int E) {
    int t = blockIdx.x * 256 + threadIdx.x;
    if (t < E) {
        atomicAdd(&deg[nidx[t]], 1);
        atomicAdd(&deg[N + eidx[t]], 1);
    }
}

// block = 256 threads, 4 elems/thread -> 1024 elems/block
__global__ __launch_bounds__(256) void scan_blocks(const int* __restrict__ in,
                                                   int* __restrict__ out,
                                                   int* __restrict__ partials, int n) {
    __shared__ int s[256];
    const int base = blockIdx.x * 1024;
    const int t = threadIdx.x;
    int v[4], sum = 0;
#pragma unroll
    for (int i = 0; i < 4; i++) {
        const int idx = base + t * 4 + i;
        v[i] = (idx < n) ? in[idx] : 0;
        sum += v[i];
    }
    s[t] = sum;
    __syncthreads();
    for (int o = 1; o < 256; o <<= 1) {
        int x = 0;
        if (t >= o) x = s[t - o];
        __syncthreads();
        if (t >= o) s[t] += x;
        __syncthreads();
    }
    if (t == 255) partials[blockIdx.x] = s[255];
    int run = (t == 0) ? 0 : s[t - 1];
#pragma unroll
    for (int i = 0; i < 4; i++) {
        const int idx = base + t * 4 + i;
        if (idx < n) out[idx] = run;
        run += v[i];
    }
}

__global__ __launch_bounds__(256) void scan_partials(int* __restrict__ partials, int P) {
    __shared__ int s[256];
    const int t = threadIdx.x;
    s[t] = (t < P) ? partials[t] : 0;
    __syncthreads();
    for (int o = 1; o < 256; o <<= 1) {
        int x = 0;
        if (t >= o) x = s[t - o];
        __syncthreads();
        if (t >= o) s[t] += x;
        __syncthreads();
    }
    if (t < P) partials[t] = (t == 0) ? 0 : s[t - 1];
}

__global__ __launch_bounds__(256) void scan_add(int* __restrict__ off,
                                                int* __restrict__ cursor,
                                                const int* __restrict__ partials,
                                                int n, int total) {
    const int idx = blockIdx.x * 256 + threadIdx.x;
    if (idx < n) {
        const int v = off[idx] + partials[idx >> 10];
        off[idx] = v;
        cursor[idx] = v;
    }
    if (idx == 0) off[n] = total;
}

__global__ __launch_bounds__(256) void build_csr(const int* __restrict__ nidx,
                                                 const int* __restrict__ eidx,
                                                 int* __restrict__ cursor,
                                                 int* __restrict__ srcidx,
                                                 int N, int E) {
    int e = blockIdx.x * 256 + threadIdx.x;
    if (e < E) {
        const int vn = nidx[e], ve = eidx[e];
        const int pn = atomicAdd(&cursor[vn], 1);
        srcidx[pn] = ve;
        const int pe = atomicAdd(&cursor[N + ve], 1);
        srcidx[pe] = vn;
    }
}

// deg int -> 1/deg float (in place: reads int, writes float to separate buf)
__global__ __launch_bounds__(256) void invert_deg_int(const int* __restrict__ deg,
                                                      float* __restrict__ inv, int n) {
    int t = blockIdx.x * 256 + threadIdx.x;
    if (t < n) {
        const int v = deg[t];
        inv[t] = (v > 0) ? 1.0f / (float)v : 0.f;
    }
}

// ---------------------------------------------------------------------------
// CSR gather: dst[r] = (scale?scale[r]:1) * sum_{j in [off[r],off[r+1])} src[srcidx[j]]
// D=256: one wave per row (64 lanes x float4). D=64: 16 lanes per row.
// ---------------------------------------------------------------------------
__global__ __launch_bounds__(256) void gather_rows_256(const float* __restrict__ src,
                                                       const int* __restrict__ off,
                                                       const int* __restrict__ srcidx,
                                                       const float* __restrict__ scale,
                                                       float* __restrict__ dst, int Nn) {
    const int row = blockIdx.x * 4 + (threadIdx.x >> 6);
    if (row >= Nn) return;
    const int c = (threadIdx.x & 63) << 2;
    const int j0 = off[row], j1 = off[row + 1];
    float4 acc = make_float4(0.f, 0.f, 0.f, 0.f);
    int j = j0;
    for (; j + 1 < j1; j += 2) {
        const int s0 = srcidx[j];
        const int s1 = srcidx[j + 1];
        const float4 v0 = *(const float4*)&src[(size_t)s0 * 256 + c];
        const float4 v1 = *(const float4*)&src[(size_t)s1 * 256 + c];
        acc.x += v0.x + v1.x; acc.y += v0.y + v1.y;
        acc.z += v0.z + v1.z; acc.w += v0.w + v1.w;
    }
    if (j < j1) {
        const int s0 = srcidx[j];
        const float4 v0 = *(const float4*)&src[(size_t)s0 * 256 + c];
        acc.x += v0.x; acc.y += v0.y; acc.z += v0.z; acc.w += v0.w;
    }
    if (scale) {
        const float s = scale[row];
        acc.x *= s; acc.y *= s; acc.z *= s; acc.w *= s;
    }
    *(float4*)&dst[(size_t)row * 256 + c] = acc;
}

__global__ __launch_bounds__(256) void gather_rows_64(const float* __restrict__ src,
                                                      const int* __restrict__ off,
                                                      const int* __restrict__ srcidx,
                                                      const float* __restrict__ scale,
                                                      float* __restrict__ dst, int Nn) {
    const int row = blockIdx.x * 16 + (threadIdx.x >> 4);
    if (row >= Nn) return;
    const int c = (threadIdx.x & 15) << 2;
    const int j0 = off[row], j1 = off[row + 1];
    float4 acc = make_float4(0.f, 0.f, 0.f, 0.f);
    int j = j0;
    for (; j + 1 < j1; j += 2) {
        const int s0 = srcidx[j];
        const int s1 = srcidx[j + 1];
        const float4 v0 = *(const float4*)&src[(size_t)s0 * 64 + c];
        const float4 v1 = *(const float4*)&src[(size_t)s1 * 64 + c];
        acc.x += v0.x + v1.x; acc.y += v0.y + v1.y;
        acc.z += v0.z + v1.z; acc.w += v0.w + v1.w;
    }
    if (j < j1) {
        const int s0 = srcidx[j];
        const float4 v0 = *(const float4*)&src[(size_t)s0 * 64 + c];
        acc.x += v0.x; acc.y += v0.y; acc.z += v0.z; acc.w += v0.w;
    }
    if (scale) {
        const float s = scale[row];
        acc.x *= s; acc.y *= s; acc.z *= s; acc.w *= s;
    }
    *(float4*)&dst[(size_t)row * 64 + c] = acc;
}

// ---------------------------------------------------------------------------
// f32 GEMM: C[M,Nc] = f(A)[M,K] @ B[K,Nc]
// optional pre-transform on A: a_eff = relu(pre_scale[row]*a + pre_bias[col])
// ---------------------------------------------------------------------------
__global__ __launch_bounds__(256) void gemm_f32(const float* __restrict__ A,
                                                const float* __restrict__ B,
                                                float* __restrict__ C,
                                                int M, int K, int Nc,
                                                const float* __restrict__ pre_scale,
                                                const float* __restrict__ pre_bias) {
    __shared__ float As[16][68];
    __shared__ float Bs[16][64];
    const int tid = threadIdx.x;
    const int bm = blockIdx.y * 64;
    const int bn = blockIdx.x * 64;
    const int tm = (tid >> 4) << 2;
    const int tn = (tid & 15) << 2;
    const int arow = tid >> 2;
    const int akq  = (tid & 3) << 2;
    const int brow = tid >> 4;
    const int bnq  = (tid & 15) << 2;

    float acc[4][4] = {{0.f}};

    for (int k0 = 0; k0 < K; k0 += 16) {
        float4 av = make_float4(0.f, 0.f, 0.f, 0.f);
        const int gr = bm + arow;
        if (gr < M) {
            av = *(const float4*)&A[(size_t)gr * K + k0 + akq];
            if (pre_scale) {
                const float s = pre_scale[gr];
                av.x = fmaxf(fmaf(av.x, s, pre_bias[k0 + akq + 0]), 0.f);
                av.y = fmaxf(fmaf(av.y, s, pre_bias[k0 + akq + 1]), 0.f);
                av.z = fmaxf(fmaf(av.z, s, pre_bias[k0 + akq + 2]), 0.f);
                av.w = fmaxf(fmaf(av.w, s, pre_bias[k0 + akq + 3]), 0.f);
            }
        }
        const float4 bv = *(const float4*)&B[(size_t)(k0 + brow) * Nc + bn + bnq];
        As[akq + 0][arow] = av.x;
        As[akq + 1][arow] = av.y;
        As[akq + 2][arow] = av.z;
        As[akq + 3][arow] = av.w;
        *(float4*)&Bs[brow][bnq] = bv;
        __syncthreads();
#pragma unroll
        for (int kk = 0; kk < 16; kk++) {
            const float a0 = As[kk][tm + 0];
            const float a1 = As[kk][tm + 1];
            const float a2 = As[kk][tm + 2];
            const float a3 = As[kk][tm + 3];
            const float4 b = *(const float4*)&Bs[kk][tn];
            acc[0][0] = fmaf(a0, b.x, acc[0][0]);
            acc[0][1] = fmaf(a0, b.y, acc[0][1]);
            acc[0][2] = fmaf(a0, b.z, acc[0][2]);
            acc[0][3] = fmaf(a0, b.w, acc[0][3]);
            acc[1][0] = fmaf(a1, b.x, acc[1][0]);
            acc[1][1] = fmaf(a1, b.y, acc[1][1]);
            acc[1][2] = fmaf(a1, b.z, acc[1][2]);
            acc[1][3] = fmaf(a1, b.w, acc[1][3]);
            acc[2][0] = fmaf(a2, b.x, acc[2][0]);
            acc[2][1] = fmaf(a2, b.y, acc[2][1]);
            acc[2][2] = fmaf(a2, b.z, acc[2][2]);
            acc[2][3] = fmaf(a2, b.w, acc[2][3]);
            acc[3][0] = fmaf(a3, b.x, acc[3][0]);
            acc[3][1] = fmaf(a3, b.y, acc[3][1]);
            acc[3][2] = fmaf(a3, b.z, acc[3][2]);
            acc[3][3] = fmaf(a3, b.w, acc[3][3]);
        }
        __syncthreads();
    }
#pragma unroll
    for (int r = 0; r < 4; r++) {
        const int gr = bm + tm + r;
        if (gr < M)
            *(float4*)&C[(size_t)gr * Nc + bn + tn] =
                make_float4(acc[r][0], acc[r][1], acc[r][2], acc[r][3]);
    }
}

// ---------------------------------------------------------------------------
// h2 = relu(d_inv[row]*raw + b2[col]) over [Nn, 64]
// ---------------------------------------------------------------------------
__global__ __launch_bounds__(256) void finalize_h2(const float* __restrict__ raw,
                                                   const float* __restrict__ d_inv,
                                                   const float* __restrict__ b2,
                                                   float* __restrict__ out, int Nn) {
    const int t = blockIdx.x * 256 + threadIdx.x;
    if (t >= Nn * 16) return;
    const int r = t >> 4;
    const int c = (t & 15) << 2;
    const float s = d_inv[r];
    const float4 v = *(const float4*)&raw[(size_t)t * 4];
    float4 o;
    o.x = fmaxf(fmaf(v.x, s, b2[c + 0]), 0.f);
    o.y = fmaxf(fmaf(v.y, s, b2[c + 1]), 0.f);
    o.z = fmaxf(fmaf(v.z, s, b2[c + 2]), 0.f);
    o.w = fmaxf(fmaf(v.w, s, b2[c + 3]), 0.f);
    *(float4*)&out[(size_t)t * 4] = o;
}

// ---------------------------------------------------------------------------
// hyperedge embedding
// ---------------------------------------------------------------------------
__global__ __launch_bounds__(256) void hye_emb_kernel(const float* __restrict__ emb,
                                                      const int* __restrict__ hnode,
                                                      const float* __restrict__ hlen,
                                                      float* __restrict__ out, int Nn) {
    const int r = blockIdx.x * 16 + (threadIdx.x >> 4);
    const int c = (threadIdx.x & 15) << 2;
    if (r >= Nn) return;
    const int* hp = &hnode[(size_t)r * 16];
    float4 acc = make_float4(0.f, 0.f, 0.f, 0.f);
#pragma unroll
    for (int l = 0; l < 16; l++) {
        const int idx = hp[l];
        if (idx > 0) {
            const float4 v = *(const float4*)&emb[(size_t)(idx - 1) * 64 + c];
            acc.x += v.x; acc.y += v.y; acc.z += v.z; acc.w += v.w;
        }
    }
    const float inv = 1.0f / (hlen[r] + 1e-15f);
    acc.x *= inv; acc.y *= inv; acc.z *= inv; acc.w *= inv;
    *(float4*)&out[(size_t)r * 64 + c] = acc;
}

// ---------------------------------------------------------------------------
// attention scores
// ---------------------------------------------------------------------------
__global__ __launch_bounds__(256) void attn_score(const float* __restrict__ z0,
                                                  const float* __restrict__ z1,
                                                  const float* __restrict__ z2,
                                                  const float* __restrict__ z3,
                                                  const float* __restrict__ W1,
                                                  const float* __restrict__ b1v,
                                                  const float* __restrict__ W2v,
                                                  float* __restrict__ accp, int Nn) {
    __shared__ float W1s[64 * 128];
    __shared__ float b1s[128];
    __shared__ float W2s[128];
    const int tid = threadIdx.x;
    for (int t = tid; t < 64 * 128; t += 256) W1s[t] = W1[t];
    if (tid < 128) { b1s[tid] = b1v[tid]; W2s[tid] = W2v[tid]; }
    __syncthreads();

    const int i = blockIdx.x * 64 + (tid >> 2);
    const int j = tid & 3;
    const float* zp = (j == 0) ? z0 : (j == 1) ? z1 : (j == 2) ? z2 : z3;

    float val = 0.f;
    if (i < Nn) {
        float zr[64];
        const float4* zrow = (const float4*)(zp + (size_t)i * 64);
#pragma unroll
        for (int q = 0; q < 16; q++) {
            const float4 v = zrow[q];
            zr[4 * q + 0] = v.x; zr[4 * q + 1] = v.y;
            zr[4 * q + 2] = v.z; zr[4 * q + 3] = v.w;
        }
        for (int h = 0; h < HATT; h += 4) {
            float s0 = b1s[h + 0], s1 = b1s[h + 1], s2 = b1s[h + 2], s3 = b1s[h + 3];
#pragma unroll
            for (int k = 0; k < 64; k++) {
                const float4 wv = *(const float4*)&W1s[k * 128 + h];
                const float zk = zr[k];
                s0 = fmaf(zk, wv.x, s0);
                s1 = fmaf(zk, wv.y, s1);
                s2 = fmaf(zk, wv.z, s2);
                s3 = fmaf(zk, wv.w, s3);
            }
            val += tanhf(s0) * W2s[h + 0] + tanhf(s1) * W2s[h + 1] +
                   tanhf(s2) * W2s[h + 2] + tanhf(s3) * W2s[h + 3];
        }
    }
#pragma unroll
    for (int off = 32; off >= 4; off >>= 1) val += __shfl_down(val, off, 64);
    if ((tid & 63) < 4) atomicAdd(&accp[j], val);
}

__global__ void softmax_beta(const float* __restrict__ acc, float* __restrict__ beta,
                             float invN) {
    const int t = threadIdx.x;
    if (t < 2) {
        const float* a = acc + 4 * t;
        float* b = beta + 4 * t;
        float w[4], m = -1e30f;
#pragma unroll
        for (int i = 0; i < 4; i++) { w[i] = a[i] * invN; m = fmaxf(m, w[i]); }
        float s = 0.f;
#pragma unroll
        for (int i = 0; i < 4; i++) { w[i] = expf(w[i] - m); s += w[i]; }
#pragma unroll
        for (int i = 0; i < 4; i++) b[i] = w[i] / s;
    }
}

__global__ __launch_bounds__(256) void weighted_sum(const float* __restrict__ z0,
                                                    const float* __restrict__ z1,
                                                    const float* __restrict__ z2,
                                                    const float* __restrict__ z3,
                                                    const float* __restrict__ beta,
                                                    float* __restrict__ out, int Nn) {
    const int t = blockIdx.x * 256 + threadIdx.x;
    if (t >= Nn * 16) return;
    const float b0 = beta[0], b1 = beta[1], b2 = beta[2], b3 = beta[3];
    const float4 v0 = *(const float4*)&z0[(size_t)t * 4];
    const float4 v1 = *(const float4*)&z1[(size_t)t * 4];
    const float4 v2 = *(const float4*)&z2[(size_t)t * 4];
    const float4 v3 = *(const float4*)&z3[(size_t)t * 4];
    float4 o;
    o.x = b0 * v0.x + b1 * v1.x + b2 * v2.x + b3 * v3.x;
    o.y = b0 * v0.y + b1 * v1.y + b2 * v2.y + b3 * v3.y;
    o.z = b0 * v0.z + b1 * v1.z + b2 * v2.z + b3 * v3.z;
    o.w = b0 * v0.w + b1 * v1.w + b2 * v2.w + b3 * v3.w;
    *(float4*)&out[(size_t)t * 4] = o;
}

// ---------------------------------------------------------------------------
extern "C" void kernel_launch(void* const* d_in, const int* in_sizes, int n_in,
                              void* d_out, int out_size, void* d_ws, size_t ws_size,
                              hipStream_t stream) {
    const int Nn = in_sizes[0] / NF;   // 50000
    const int E  = in_sizes[1] / 2;    // 800000
    const int N2 = 2 * Nn;

    const float* x[4];
    const int*   ei[4];
    const int*   hnode[4];
    const float* hlen[4];
    for (int g = 0; g < 4; g++) {
        x[g]     = (const float*)d_in[4 * g + 0];
        ei[g]    = (const int*)d_in[4 * g + 1];
        hnode[g] = (const int*)d_in[4 * g + 2];
        hlen[g]  = (const float*)d_in[4 * g + 3];
    }
    const float* W1   = (const float*)d_in[16];
    const float* b1   = (const float*)d_in[17];
    const float* W2   = (const float*)d_in[18];
    const float* b2   = (const float*)d_in[19];
    const float* acW1 = (const float*)d_in[20];
    const float* acb1 = (const float*)d_in[21];
    const float* acW2 = (const float*)d_in[22];
    const float* amW1 = (const float*)d_in[23];
    const float* amb1 = (const float*)d_in[24];
    const float* amW2 = (const float*)d_in[25];

    // workspace layout
    float* ws = (float*)d_ws;
    size_t o = 0;
    float* bufA = ws + o; o += (size_t)Nn * DD1;
    float* bufB = ws + o; o += (size_t)Nn * DD1;
    float* dinv = ws + o; o += N2;          // [d_inv(N) | b_inv(N)]
    float* h2[4];
    float* hemb[4];
    for (int g = 0; g < 4; g++) { h2[g]   = ws + o; o += (size_t)Nn * DD2; }
    for (int g = 0; g < 4; g++) { hemb[g] = ws + o; o += (size_t)Nn * DD2; }
    float* accw = ws + o; o += 8;
    float* beta = ws + o; o += 8;
    int* iws = (int*)(ws + o);
    size_t io = 0;
    int* deg_i    = iws + io; io += N2;
    int* off      = iws + io; io += N2 + 1;
    int* cursor   = iws + io; io += N2;
    int* partials = iws + io; io += 256;
    int* srcidx   = iws + io; io += (size_t)2 * E;

    const int nScanBlocks = cdiv(N2, 1024);

    for (int g = 0; g < 4; g++) {
        const int* nidx = ei[g];
        const int* eidx = ei[g] + E;
        const int* off_n = off;        // CSR by nidx (edge -> node passes)
        const int* off_e = off + Nn;   // CSR by eidx (node -> edge passes)
        const float* d_inv = dinv;
        const float* b_inv = dinv + Nn;

        // ---- build CSRs ----
        hipMemsetAsync(deg_i, 0, (size_t)N2 * sizeof(int), stream);
        count_deg_int<<<cdiv(E, 256), 256, 0, stream>>>(nidx, eidx, deg_i, Nn, E);
        scan_blocks<<<nScanBlocks, 256, 0, stream>>>(deg_i, off, partials, N2);
        scan_partials<<<1, 256, 0, stream>>>(partials, nScanBlocks);
        scan_add<<<cdiv(N2, 256), 256, 0, stream>>>(off, cursor, partials, N2, 2 * E);
        build_csr<<<cdiv(E, 256), 256, 0, stream>>>(nidx, eidx, cursor, srcidx, Nn, E);
        invert_deg_int<<<cdiv(N2, 256), 256, 0, stream>>>(deg_i, dinv, N2);

        // ---- hconv1 ----
        // xlin = x @ W1   [Nn,128]@[128,256] -> bufA
        gemm_f32<<<dim3(DD1 / 64, cdiv(Nn, 64)), 256, 0, stream>>>(
            x[g], W1, bufA, Nn, NF, DD1, nullptr, nullptr);
        // e1 = b_inv * gather(xlin, CSR_e) -> bufB
        gather_rows_256<<<cdiv(Nn, 4), 256, 0, stream>>>(bufA, off_e, srcidx, b_inv, bufB, Nn);
        // h1raw = gather(e1, CSR_n) -> bufA
        gather_rows_256<<<cdiv(Nn, 4), 256, 0, stream>>>(bufB, off_n, srcidx, nullptr, bufA, Nn);

        // ---- hconv2 ----
        // x2lin = relu(d_inv*h1raw + b1) @ W2  [Nn,256]@[256,64] -> bufB
        gemm_f32<<<dim3(1, cdiv(Nn, 64)), 256, 0, stream>>>(
            bufA, W2, bufB, Nn, DD1, DD2, d_inv, b1);
        // e2 = b_inv * gather(x2lin, CSR_e) -> bufA
        gather_rows_64<<<cdiv(Nn, 16), 256, 0, stream>>>(bufB, off_e, srcidx, b_inv, bufA, Nn);
        // h2raw = gather(e2, CSR_n) -> bufB
        gather_rows_64<<<cdiv(Nn, 16), 256, 0, stream>>>(bufA, off_n, srcidx, nullptr, bufB, Nn);
        // h2 = relu(d_inv*h2raw + b2)
        finalize_h2<<<cdiv(Nn * 16, 256), 256, 0, stream>>>(bufB, d_inv, b2, h2[g], Nn);

        // hyperedge embedding
        hye_emb_kernel<<<cdiv(Nn, 16), 256, 0, stream>>>(h2[g], hnode[g], hlen[g], hemb[g], Nn);
    }

    // ---- fusion attention ----
    hipMemsetAsync(accw, 0, 8 * sizeof(float), stream);
    attn_score<<<cdiv(Nn, 64), 256, 0, stream>>>(h2[1], hemb[0], h2[2], hemb[2],
                                                 acW1, acb1, acW2, accw + 0, Nn);
    attn_score<<<cdiv(Nn, 64), 256, 0, stream>>>(h2[0], hemb[1], h2[3], hemb[3],
                                                 amW1, amb1, amW2, accw + 4, Nn);
    softmax_beta<<<1, 64, 0, stream>>>(accw, beta, 1.0f / (float)Nn);

    float* out = (float*)d_out;
    weighted_sum<<<cdiv(Nn * 16, 256), 256, 0, stream>>>(h2[1], hemb[0], h2[2], hemb[2],
                                                         beta + 0, out, Nn);
    weighted_sum<<<cdiv(Nn * 16, 256), 256, 0, stream>>>(h2[0], hemb[1], h2[3], hemb[3],
                                                         beta + 4, out + (size_t)Nn * DD2, Nn);
}

// Round 3
// 2731.509 us; speedup vs baseline: 10.3228x; 1.1361x over previous
//
#include <hip/hip_runtime.h>
#include <hip/hip_bf16.h>

// Problem constants
#define NF   128   // in_channels
#define DD1  256   // dim_1
#define DD2  64    // dim_1/4
#define HATT 128   // attention hidden

static inline int cdiv(int a, int b) { return (a + b - 1) / b; }

// ---------------------------------------------------------------------------
// CSR build: degree count (int), hierarchical exclusive scan, bucket fill.
// ---------------------------------------------------------------------------
__global__ __launch_bounds__(256) void count_deg_int(const int* __restrict__ nidx,
                                                     const int* __restrict__ eidx,
                                                     int* __restrict__ deg,
                                                     int N, int E) {
    int t = blockIdx.x * 256 + threadIdx.x;
    if (t < E) {
        atomicAdd(&deg[nidx[t]], 1);
        atomicAdd(&deg[N + eidx[t]], 1);
    }
}

__global__ __launch_bounds__(256) void scan_blocks(const int* __restrict__ in,
                                                   int* __restrict__ out,
                                                   int* __restrict__ partials, int n) {
    __shared__ int s[256];
    const int base = blockIdx.x * 1024;
    const int t = threadIdx.x;
    int v[4], sum = 0;
#pragma unroll
    for (int i = 0; i < 4; i++) {
        const int idx = base + t * 4 + i;
        v[i] = (idx < n) ? in[idx] : 0;
        sum += v[i];
    }
    s[t] = sum;
    __syncthreads();
    for (int o = 1; o < 256; o <<= 1) {
        int x = 0;
        if (t >= o) x = s[t - o];
        __syncthreads();
        if (t >= o) s[t] += x;
        __syncthreads();
    }
    if (t == 255) partials[blockIdx.x] = s[255];
    int run = (t == 0) ? 0 : s[t - 1];
#pragma unroll
    for (int i = 0; i < 4; i++) {
        const int idx = base + t * 4 + i;
        if (idx < n) out[idx] = run;
        run += v[i];
    }
}

__global__ __launch_bounds__(256) void scan_partials(int* __restrict__ partials, int P) {
    __shared__ int s[256];
    const int t = threadIdx.x;
    s[t] = (t < P) ? partials[t] : 0;
    __syncthreads();
    for (int o = 1; o < 256; o <<= 1) {
        int x = 0;
        if (t >= o) x = s[t - o];
        __syncthreads();
        if (t >= o) s[t] += x;
        __syncthreads();
    }
    if (t < P) partials[t] = (t == 0) ? 0 : s[t - 1];
}

__global__ __launch_bounds__(256) void scan_add(int* __restrict__ off,
                                                int* __restrict__ cursor,
                                                const int* __restrict__ partials,
                                                int n, int total) {
    const int idx = blockIdx.x * 256 + threadIdx.x;
    if (idx < n) {
        const int v = off[idx] + partials[idx >> 10];
        off[idx] = v;
        cursor[idx] = v;
    }
    if (idx == 0) off[n] = total;
}

__global__ __launch_bounds__(256) void build_csr(const int* __restrict__ nidx,
                                                 const int* __restrict__ eidx,
                                                 int* __restrict__ cursor,
                                                 int* __restrict__ srcidx,
                                                 int N, int E) {
    int e = blockIdx.x * 256 + threadIdx.x;
    if (e < E) {
        const int vn = nidx[e], ve = eidx[e];
        const int pn = atomicAdd(&cursor[vn], 1);
        srcidx[pn] = ve;
        const int pe = atomicAdd(&cursor[N + ve], 1);
        srcidx[pe] = vn;
    }
}

__global__ __launch_bounds__(256) void invert_deg_int(const int* __restrict__ deg,
                                                      float* __restrict__ inv, int n) {
    int t = blockIdx.x * 256 + threadIdx.x;
    if (t < n) {
        const int v = deg[t];
        inv[t] = (v > 0) ? 1.0f / (float)v : 0.f;
    }
}

// ---------------------------------------------------------------------------
// CSR gather, D=256: one wave per row. Wave-uniform offsets/indices via
// readfirstlane -> scalar loads; unroll 4 with dual accumulators.
// ---------------------------------------------------------------------------
__global__ __launch_bounds__(256) void gather_rows_256(const float* __restrict__ src,
                                                       const int* __restrict__ off,
                                                       const int* __restrict__ srcidx,
                                                       const float* __restrict__ scale,
                                                       float* __restrict__ dst, int Nn) {
    const int row = blockIdx.x * 4 + (threadIdx.x >> 6);
    if (row >= Nn) return;
    const int rowu = __builtin_amdgcn_readfirstlane(row);
    const int c = (threadIdx.x & 63) << 2;
    const int j0 = off[rowu], j1 = off[rowu + 1];
    float4 a0 = make_float4(0.f, 0.f, 0.f, 0.f);
    float4 a1 = make_float4(0.f, 0.f, 0.f, 0.f);
    int j = j0;
    for (; j + 3 < j1; j += 4) {
        const int s0 = srcidx[j + 0];
        const int s1 = srcidx[j + 1];
        const int s2 = srcidx[j + 2];
        const int s3 = srcidx[j + 3];
        const float4 v0 = *(const float4*)&src[(size_t)s0 * 256 + c];
        const float4 v1 = *(const float4*)&src[(size_t)s1 * 256 + c];
        const float4 v2 = *(const float4*)&src[(size_t)s2 * 256 + c];
        const float4 v3 = *(const float4*)&src[(size_t)s3 * 256 + c];
        a0.x += v0.x + v1.x; a0.y += v0.y + v1.y;
        a0.z += v0.z + v1.z; a0.w += v0.w + v1.w;
        a1.x += v2.x + v3.x; a1.y += v2.y + v3.y;
        a1.z += v2.z + v3.z; a1.w += v2.w + v3.w;
    }
    for (; j < j1; j++) {
        const int s0 = srcidx[j];
        const float4 v0 = *(const float4*)&src[(size_t)s0 * 256 + c];
        a0.x += v0.x; a0.y += v0.y; a0.z += v0.z; a0.w += v0.w;
    }
    float4 acc = make_float4(a0.x + a1.x, a0.y + a1.y, a0.z + a1.z, a0.w + a1.w);
    if (scale) {
        const float s = scale[rowu];
        acc.x *= s; acc.y *= s; acc.z *= s; acc.w *= s;
    }
    *(float4*)&dst[(size_t)row * 256 + c] = acc;
}

// ---------------------------------------------------------------------------
// CSR gather, D=64: 16 lanes per row. Optional fused epilogue:
//   post_bias != null:  out = relu(scale[row]*sum + post_bias[col])
//   else if scale:      out = scale[row]*sum
// ---------------------------------------------------------------------------
__global__ __launch_bounds__(256) void gather_rows_64(const float* __restrict__ src,
                                                      const int* __restrict__ off,
                                                      const int* __restrict__ srcidx,
                                                      const float* __restrict__ scale,
                                                      const float* __restrict__ post_bias,
                                                      float* __restrict__ dst, int Nn) {
    const int row = blockIdx.x * 16 + (threadIdx.x >> 4);
    if (row >= Nn) return;
    const int c = (threadIdx.x & 15) << 2;
    const int j0 = off[row], j1 = off[row + 1];
    float4 a0 = make_float4(0.f, 0.f, 0.f, 0.f);
    float4 a1 = make_float4(0.f, 0.f, 0.f, 0.f);
    int j = j0;
    for (; j + 1 < j1; j += 2) {
        const int s0 = srcidx[j];
        const int s1 = srcidx[j + 1];
        const float4 v0 = *(const float4*)&src[(size_t)s0 * 64 + c];
        const float4 v1 = *(const float4*)&src[(size_t)s1 * 64 + c];
        a0.x += v0.x; a0.y += v0.y; a0.z += v0.z; a0.w += v0.w;
        a1.x += v1.x; a1.y += v1.y; a1.z += v1.z; a1.w += v1.w;
    }
    if (j < j1) {
        const int s0 = srcidx[j];
        const float4 v0 = *(const float4*)&src[(size_t)s0 * 64 + c];
        a0.x += v0.x; a0.y += v0.y; a0.z += v0.z; a0.w += v0.w;
    }
    float4 acc = make_float4(a0.x + a1.x, a0.y + a1.y, a0.z + a1.z, a0.w + a1.w);
    if (scale) {
        const float s = scale[row];
        acc.x *= s; acc.y *= s; acc.z *= s; acc.w *= s;
    }
    if (post_bias) {
        acc.x = fmaxf(acc.x + post_bias[c + 0], 0.f);
        acc.y = fmaxf(acc.y + post_bias[c + 1], 0.f);
        acc.z = fmaxf(acc.z + post_bias[c + 2], 0.f);
        acc.w = fmaxf(acc.w + post_bias[c + 3], 0.f);
    }
    *(float4*)&dst[(size_t)row * 64 + c] = acc;
}

// ---------------------------------------------------------------------------
// f32 GEMM: C[M,Nc] = f(A)[M,K] @ B[K,Nc]
// ---------------------------------------------------------------------------
__global__ __launch_bounds__(256) void gemm_f32(const float* __restrict__ A,
                                                const float* __restrict__ B,
                                                float* __restrict__ C,
                                                int M, int K, int Nc,
                                                const float* __restrict__ pre_scale,
                                                const float* __restrict__ pre_bias) {
    __shared__ float As[16][68];
    __shared__ float Bs[16][64];
    const int tid = threadIdx.x;
    const int bm = blockIdx.y * 64;
    const int bn = blockIdx.x * 64;
    const int tm = (tid >> 4) << 2;
    const int tn = (tid & 15) << 2;
    const int arow = tid >> 2;
    const int akq  = (tid & 3) << 2;
    const int brow = tid >> 4;
    const int bnq  = (tid & 15) << 2;

    float acc[4][4] = {{0.f}};

    for (int k0 = 0; k0 < K; k0 += 16) {
        float4 av = make_float4(0.f, 0.f, 0.f, 0.f);
        const int gr = bm + arow;
        if (gr < M) {
            av = *(const float4*)&A[(size_t)gr * K + k0 + akq];
            if (pre_scale) {
                const float s = pre_scale[gr];
                av.x = fmaxf(fmaf(av.x, s, pre_bias[k0 + akq + 0]), 0.f);
                av.y = fmaxf(fmaf(av.y, s, pre_bias[k0 + akq + 1]), 0.f);
                av.z = fmaxf(fmaf(av.z, s, pre_bias[k0 + akq + 2]), 0.f);
                av.w = fmaxf(fmaf(av.w, s, pre_bias[k0 + akq + 3]), 0.f);
            }
        }
        const float4 bv = *(const float4*)&B[(size_t)(k0 + brow) * Nc + bn + bnq];
        As[akq + 0][arow] = av.x;
        As[akq + 1][arow] = av.y;
        As[akq + 2][arow] = av.z;
        As[akq + 3][arow] = av.w;
        *(float4*)&Bs[brow][bnq] = bv;
        __syncthreads();
#pragma unroll
        for (int kk = 0; kk < 16; kk++) {
            const float4 a4 = *(const float4*)&As[kk][tm];
            const float4 b = *(const float4*)&Bs[kk][tn];
            acc[0][0] = fmaf(a4.x, b.x, acc[0][0]);
            acc[0][1] = fmaf(a4.x, b.y, acc[0][1]);
            acc[0][2] = fmaf(a4.x, b.z, acc[0][2]);
            acc[0][3] = fmaf(a4.x, b.w, acc[0][3]);
            acc[1][0] = fmaf(a4.y, b.x, acc[1][0]);
            acc[1][1] = fmaf(a4.y, b.y, acc[1][1]);
            acc[1][2] = fmaf(a4.y, b.z, acc[1][2]);
            acc[1][3] = fmaf(a4.y, b.w, acc[1][3]);
            acc[2][0] = fmaf(a4.z, b.x, acc[2][0]);
            acc[2][1] = fmaf(a4.z, b.y, acc[2][1]);
            acc[2][2] = fmaf(a4.z, b.z, acc[2][2]);
            acc[2][3] = fmaf(a4.z, b.w, acc[2][3]);
            acc[3][0] = fmaf(a4.w, b.x, acc[3][0]);
            acc[3][1] = fmaf(a4.w, b.y, acc[3][1]);
            acc[3][2] = fmaf(a4.w, b.z, acc[3][2]);
            acc[3][3] = fmaf(a4.w, b.w, acc[3][3]);
        }
        __syncthreads();
    }
#pragma unroll
    for (int r = 0; r < 4; r++) {
        const int gr = bm + tm + r;
        if (gr < M)
            *(float4*)&C[(size_t)gr * Nc + bn + tn] =
                make_float4(acc[r][0], acc[r][1], acc[r][2], acc[r][3]);
    }
}

// ---------------------------------------------------------------------------
// hyperedge embedding
// ---------------------------------------------------------------------------
__global__ __launch_bounds__(256) void hye_emb_kernel(const float* __restrict__ emb,
                                                      const int* __restrict__ hnode,
                                                      const float* __restrict__ hlen,
                                                      float* __restrict__ out, int Nn) {
    const int r = blockIdx.x * 16 + (threadIdx.x >> 4);
    const int c = (threadIdx.x & 15) << 2;
    if (r >= Nn) return;
    const int* hp = &hnode[(size_t)r * 16];
    float4 acc = make_float4(0.f, 0.f, 0.f, 0.f);
#pragma unroll
    for (int l = 0; l < 16; l++) {
        const int idx = hp[l];
        if (idx > 0) {
            const float4 v = *(const float4*)&emb[(size_t)(idx - 1) * 64 + c];
            acc.x += v.x; acc.y += v.y; acc.z += v.z; acc.w += v.w;
        }
    }
    const float inv = 1.0f / (hlen[r] + 1e-15f);
    acc.x *= inv; acc.y *= inv; acc.z *= inv; acc.w *= inv;
    *(float4*)&out[(size_t)r * 64 + c] = acc;
}

// ---------------------------------------------------------------------------
// Fusion-attention scores as a tiled GEMM with fused tanh*W2 reduce epilogue.
// grid = (cdiv(Nn,128), 8); blockIdx.y = head*4 + comp.
// Tile: 128 rows x 128 hidden, K=64 staged once. 8x8 micro-tile per thread.
// ---------------------------------------------------------------------------
struct AttnArgs {
    const float* z[8];
    const float* W1c; const float* b1c; const float* W2c;
    const float* W1m; const float* b1m; const float* W2m;
    float* accw;
    int Nn;
};

__global__ __launch_bounds__(256) void attn_gemm(AttnArgs a) {
    __shared__ float As[64][132];   // [k][m]
    __shared__ float Bs[64][128];   // [k][h]
    __shared__ float red[4];
    const int tid = threadIdx.x;
    const int gy = blockIdx.y;      // head*4 + comp
    const int head = gy >> 2;
    const float* __restrict__ z  = a.z[gy];
    const float* __restrict__ W1 = head ? a.W1m : a.W1c;
    const float* __restrict__ b1 = head ? a.b1m : a.b1c;
    const float* __restrict__ W2 = head ? a.W2m : a.W2c;
    const int m0 = blockIdx.x * 128;

    // stage A: z rows, transposed to As[k][m]
    {
        const int c4 = tid & 15;
        const int mb = tid >> 4;
#pragma unroll
        for (int i = 0; i < 8; i++) {
            const int m = mb + 16 * i;
            const int grow = m0 + m;
            float4 v = make_float4(0.f, 0.f, 0.f, 0.f);
            if (grow < a.Nn) v = *(const float4*)&z[(size_t)grow * 64 + c4 * 4];
            As[c4 * 4 + 0][m] = v.x;
            As[c4 * 4 + 1][m] = v.y;
            As[c4 * 4 + 2][m] = v.z;
            As[c4 * 4 + 3][m] = v.w;
        }
    }
    // stage B: W1 [64][128] natural layout
    {
#pragma unroll
        for (int i = 0; i < 8; i++) {
            const int f = tid + 256 * i;     // float4 index
            const int r = f >> 5, cc = (f & 31) << 2;
            *(float4*)&Bs[r][cc] = *(const float4*)&W1[(size_t)r * 128 + cc];
        }
    }
    __syncthreads();

    const int tr = (tid & 15) * 8;
    const int tc = (tid >> 4) * 8;
    float acc[8][8] = {{0.f}};
    for (int k = 0; k < 64; k++) {
        float av[8], bv[8];
        *(float4*)&av[0] = *(const float4*)&As[k][tr];
        *(float4*)&av[4] = *(const float4*)&As[k][tr + 4];
        *(float4*)&bv[0] = *(const float4*)&Bs[k][tc];
        *(float4*)&bv[4] = *(const float4*)&Bs[k][tc + 4];
#pragma unroll
        for (int r = 0; r < 8; r++)
#pragma unroll
            for (int c = 0; c < 8; c++)
                acc[r][c] = fmaf(av[r], bv[c], acc[r][c]);
    }

    // epilogue: sum_{r,c} tanh(acc + b1[c]) * W2[c]  (guarded rows)
    float w2v[8], b1v[8];
#pragma unroll
    for (int c = 0; c < 8; c++) { w2v[c] = W2[tc + c]; b1v[c] = b1[tc + c]; }
    float local = 0.f;
#pragma unroll
    for (int r = 0; r < 8; r++) {
        if (m0 + tr + r < a.Nn) {
#pragma unroll
            for (int c = 0; c < 8; c++) {
                float s = acc[r][c] + b1v[c];
                s = fminf(fmaxf(s, -15.f), 15.f);
                const float t = __expf(2.f * s);
                local += (1.f - 2.f / (t + 1.f)) * w2v[c];
            }
        }
    }
#pragma unroll
    for (int off = 32; off >= 1; off >>= 1) local += __shfl_down(local, off, 64);
    if ((tid & 63) == 0) red[tid >> 6] = local;
    __syncthreads();
    if (tid == 0) atomicAdd(&a.accw[gy], red[0] + red[1] + red[2] + red[3]);
}

__global__ void softmax_beta(const float* __restrict__ acc, float* __restrict__ beta,
                             float invN) {
    const int t = threadIdx.x;
    if (t < 2) {
        const float* a = acc + 4 * t;
        float* b = beta + 4 * t;
        float w[4], m = -1e30f;
#pragma unroll
        for (int i = 0; i < 4; i++) { w[i] = a[i] * invN; m = fmaxf(m, w[i]); }
        float s = 0.f;
#pragma unroll
        for (int i = 0; i < 4; i++) { w[i] = expf(w[i] - m); s += w[i]; }
#pragma unroll
        for (int i = 0; i < 4; i++) b[i] = w[i] / s;
    }
}

__global__ __launch_bounds__(256) void weighted_sum(const float* __restrict__ z0,
                                                    const float* __restrict__ z1,
                                                    const float* __restrict__ z2,
                                                    const float* __restrict__ z3,
                                                    const float* __restrict__ beta,
                                                    float* __restrict__ out, int Nn) {
    const int t = blockIdx.x * 256 + threadIdx.x;
    if (t >= Nn * 16) return;
    const float b0 = beta[0], b1 = beta[1], b2 = beta[2], b3 = beta[3];
    const float4 v0 = *(const float4*)&z0[(size_t)t * 4];
    const float4 v1 = *(const float4*)&z1[(size_t)t * 4];
    const float4 v2 = *(const float4*)&z2[(size_t)t * 4];
    const float4 v3 = *(const float4*)&z3[(size_t)t * 4];
    float4 o;
    o.x = b0 * v0.x + b1 * v1.x + b2 * v2.x + b3 * v3.x;
    o.y = b0 * v0.y + b1 * v1.y + b2 * v2.y + b3 * v3.y;
    o.z = b0 * v0.z + b1 * v1.z + b2 * v2.z + b3 * v3.z;
    o.w = b0 * v0.w + b1 * v1.w + b2 * v2.w + b3 * v3.w;
    *(float4*)&out[(size_t)t * 4] = o;
}

// ---------------------------------------------------------------------------
extern "C" void kernel_launch(void* const* d_in, const int* in_sizes, int n_in,
                              void* d_out, int out_size, void* d_ws, size_t ws_size,
                              hipStream_t stream) {
    const int Nn = in_sizes[0] / NF;   // 50000
    const int E  = in_sizes[1] / 2;    // 800000
    const int N2 = 2 * Nn;

    const float* x[4];
    const int*   ei[4];
    const int*   hnode[4];
    const float* hlen[4];
    for (int g = 0; g < 4; g++) {
        x[g]     = (const float*)d_in[4 * g + 0];
        ei[g]    = (const int*)d_in[4 * g + 1];
        hnode[g] = (const int*)d_in[4 * g + 2];
        hlen[g]  = (const float*)d_in[4 * g + 3];
    }
    const float* W1   = (const float*)d_in[16];
    const float* b1   = (const float*)d_in[17];
    const float* W2   = (const float*)d_in[18];
    const float* b2   = (const float*)d_in[19];
    const float* acW1 = (const float*)d_in[20];
    const float* acb1 = (const float*)d_in[21];
    const float* acW2 = (const float*)d_in[22];
    const float* amW1 = (const float*)d_in[23];
    const float* amb1 = (const float*)d_in[24];
    const float* amW2 = (const float*)d_in[25];

    // workspace layout
    float* ws = (float*)d_ws;
    size_t o = 0;
    float* bufA = ws + o; o += (size_t)Nn * DD1;
    float* bufB = ws + o; o += (size_t)Nn * DD1;
    float* dinv = ws + o; o += N2;          // [d_inv(N) | b_inv(N)]
    float* h2[4];
    float* hemb[4];
    for (int g = 0; g < 4; g++) { h2[g]   = ws + o; o += (size_t)Nn * DD2; }
    for (int g = 0; g < 4; g++) { hemb[g] = ws + o; o += (size_t)Nn * DD2; }
    float* accw = ws + o; o += 8;
    float* beta = ws + o; o += 8;
    int* iws = (int*)(ws + o);
    size_t io = 0;
    int* deg_i    = iws + io; io += N2;
    int* off      = iws + io; io += N2 + 1;
    int* cursor   = iws + io; io += N2;
    int* partials = iws + io; io += 256;
    int* srcidx   = iws + io; io += (size_t)2 * E;

    const int nScanBlocks = cdiv(N2, 1024);

    for (int g = 0; g < 4; g++) {
        const int* nidx = ei[g];
        const int* eidx = ei[g] + E;
        const int* off_n = off;        // CSR by nidx (edge -> node passes)
        const int* off_e = off + Nn;   // CSR by eidx (node -> edge passes)
        const float* d_inv = dinv;
        const float* b_inv = dinv + Nn;

        // ---- build CSRs ----
        hipMemsetAsync(deg_i, 0, (size_t)N2 * sizeof(int), stream);
        count_deg_int<<<cdiv(E, 256), 256, 0, stream>>>(nidx, eidx, deg_i, Nn, E);
        scan_blocks<<<nScanBlocks, 256, 0, stream>>>(deg_i, off, partials, N2);
        scan_partials<<<1, 256, 0, stream>>>(partials, nScanBlocks);
        scan_add<<<cdiv(N2, 256), 256, 0, stream>>>(off, cursor, partials, N2, 2 * E);
        build_csr<<<cdiv(E, 256), 256, 0, stream>>>(nidx, eidx, cursor, srcidx, Nn, E);
        invert_deg_int<<<cdiv(N2, 256), 256, 0, stream>>>(deg_i, dinv, N2);

        // ---- hconv1 ----
        gemm_f32<<<dim3(DD1 / 64, cdiv(Nn, 64)), 256, 0, stream>>>(
            x[g], W1, bufA, Nn, NF, DD1, nullptr, nullptr);
        gather_rows_256<<<cdiv(Nn, 4), 256, 0, stream>>>(bufA, off_e, srcidx, b_inv, bufB, Nn);
        gather_rows_256<<<cdiv(Nn, 4), 256, 0, stream>>>(bufB, off_n, srcidx, nullptr, bufA, Nn);

        // ---- hconv2 ----
        gemm_f32<<<dim3(1, cdiv(Nn, 64)), 256, 0, stream>>>(
            bufA, W2, bufB, Nn, DD1, DD2, d_inv, b1);
        gather_rows_64<<<cdiv(Nn, 16), 256, 0, stream>>>(bufB, off_e, srcidx, b_inv,
                                                         nullptr, bufA, Nn);
        // h2 = relu(d_inv * gather + b2), fused
        gather_rows_64<<<cdiv(Nn, 16), 256, 0, stream>>>(bufA, off_n, srcidx, d_inv,
                                                         b2, h2[g], Nn);

        // hyperedge embedding
        hye_emb_kernel<<<cdiv(Nn, 16), 256, 0, stream>>>(h2[g], hnode[g], hlen[g], hemb[g], Nn);
    }

    // ---- fusion attention ----
    hipMemsetAsync(accw, 0, 8 * sizeof(float), stream);
    AttnArgs aa;
    // head c comps: (x1_mc, x2_cm, x1_cc, x2_cc)
    aa.z[0] = h2[1]; aa.z[1] = hemb[0]; aa.z[2] = h2[2]; aa.z[3] = hemb[2];
    // head m comps: (x1_cm, x2_mc, x1_mm, x2_mm)
    aa.z[4] = h2[0]; aa.z[5] = hemb[1]; aa.z[6] = h2[3]; aa.z[7] = hemb[3];
    aa.W1c = acW1; aa.b1c = acb1; aa.W2c = acW2;
    aa.W1m = amW1; aa.b1m = amb1; aa.W2m = amW2;
    aa.accw = accw; aa.Nn = Nn;
    attn_gemm<<<dim3(cdiv(Nn, 128), 8), 256, 0, stream>>>(aa);
    softmax_beta<<<1, 64, 0, stream>>>(accw, beta, 1.0f / (float)Nn);

    float* out = (float*)d_out;
    weighted_sum<<<cdiv(Nn * 16, 256), 256, 0, stream>>>(h2[1], hemb[0], h2[2], hemb[2],
                                                         beta + 0, out, Nn);
    weighted_sum<<<cdiv(Nn * 16, 256), 256, 0, stream>>>(h2[0], hemb[1], h2[3], hemb[3],
                                                         beta + 4, out + (size_t)Nn * DD2, Nn);
}

// Round 4
// 1905.144 us; speedup vs baseline: 14.8004x; 1.4338x over previous
//
#include <hip/hip_runtime.h>
#include <hip/hip_bf16.h>

// Problem constants
#define NF   128   // in_channels
#define DD1  256   // dim_1
#define DD2  64    // dim_1/4
#define HATT 128   // attention hidden

static inline int cdiv(int a, int b) { return (a + b - 1) / b; }

// ---------------------------------------------------------------------------
// Pass 1: degree count + per-edge rank capture (rank < 2^16 since max deg ~45).
// rank[e] = rank_within_node_list | (rank_within_edge_list << 16)
// ---------------------------------------------------------------------------
__global__ __launch_bounds__(256) void count_rank(const int* __restrict__ nidx,
                                                  const int* __restrict__ eidx,
                                                  int* __restrict__ deg,
                                                  int* __restrict__ rank,
                                                  int N, int E) {
    int e = blockIdx.x * 256 + threadIdx.x;
    if (e < E) {
        const int vn = nidx[e], ve = eidx[e];
        const int rn = atomicAdd(&deg[vn], 1);
        const int re = atomicAdd(&deg[N + ve], 1);
        rank[e] = rn | (re << 16);
    }
}

// block = 256 threads, 4 elems/thread -> 1024 elems/block
__global__ __launch_bounds__(256) void scan_blocks(const int* __restrict__ in,
                                                   int* __restrict__ out,
                                                   int* __restrict__ partials, int n) {
    __shared__ int s[256];
    const int base = blockIdx.x * 1024;
    const int t = threadIdx.x;
    int v[4], sum = 0;
#pragma unroll
    for (int i = 0; i < 4; i++) {
        const int idx = base + t * 4 + i;
        v[i] = (idx < n) ? in[idx] : 0;
        sum += v[i];
    }
    s[t] = sum;
    __syncthreads();
    for (int o = 1; o < 256; o <<= 1) {
        int x = 0;
        if (t >= o) x = s[t - o];
        __syncthreads();
        if (t >= o) s[t] += x;
        __syncthreads();
    }
    if (t == 255) partials[blockIdx.x] = s[255];
    int run = (t == 0) ? 0 : s[t - 1];
#pragma unroll
    for (int i = 0; i < 4; i++) {
        const int idx = base + t * 4 + i;
        if (idx < n) out[idx] = run;
        run += v[i];
    }
}

__global__ __launch_bounds__(256) void scan_partials(int* __restrict__ partials, int P) {
    __shared__ int s[256];
    const int t = threadIdx.x;
    s[t] = (t < P) ? partials[t] : 0;
    __syncthreads();
    for (int o = 1; o < 256; o <<= 1) {
        int x = 0;
        if (t >= o) x = s[t - o];
        __syncthreads();
        if (t >= o) s[t] += x;
        __syncthreads();
    }
    if (t < P) partials[t] = (t == 0) ? 0 : s[t - 1];
}

__global__ __launch_bounds__(256) void scan_add(int* __restrict__ off,
                                                const int* __restrict__ partials,
                                                int n, int total) {
    const int idx = blockIdx.x * 256 + threadIdx.x;
    if (idx < n) off[idx] += partials[idx >> 10];
    if (idx == 0) off[n] = total;
}

// ---------------------------------------------------------------------------
// Pass 2: store-only CSR fill, sharded by destination-vertex range so all
// writes to a given srcidx line come from blocks with the same blockIdx&7
// (round-robin XCD assignment keeps each line in one XCD's L2).
// Correct regardless of actual block->XCD mapping.
// ---------------------------------------------------------------------------
__global__ __launch_bounds__(256) void build_fill(const int* __restrict__ nidx,
                                                  const int* __restrict__ eidx,
                                                  const int* __restrict__ rank,
                                                  const int* __restrict__ off,
                                                  int* __restrict__ srcidx,
                                                  int N, int E, int shardSize) {
    const int shard = blockIdx.x & 7;
    const int chunk = blockIdx.x >> 3;
    const int lo = shard * shardSize;
    const int hi = lo + shardSize;
    const int base = chunk * 1024;
#pragma unroll
    for (int i = 0; i < 4; i++) {
        const int e = base + i * 256 + threadIdx.x;
        if (e < E) {
            const int vn = nidx[e], ve = eidx[e];
            const int rk = rank[e];
            if (vn >= lo && vn < hi)
                srcidx[off[vn] + (rk & 0xffff)] = ve;
            if (ve >= lo && ve < hi)
                srcidx[off[N + ve] + (rk >> 16)] = vn;
        }
    }
}

__global__ __launch_bounds__(256) void invert_deg_int(const int* __restrict__ deg,
                                                      float* __restrict__ inv, int n) {
    int t = blockIdx.x * 256 + threadIdx.x;
    if (t < n) {
        const int v = deg[t];
        inv[t] = (v > 0) ? 1.0f / (float)v : 0.f;
    }
}

// ---------------------------------------------------------------------------
// CSR gather, D=128: 32 lanes per row, 8 rows per block.
// ---------------------------------------------------------------------------
__global__ __launch_bounds__(256) void gather_rows_128(const float* __restrict__ src,
                                                       const int* __restrict__ off,
                                                       const int* __restrict__ srcidx,
                                                       const float* __restrict__ scale,
                                                       float* __restrict__ dst, int Nn) {
    const int row = blockIdx.x * 8 + (threadIdx.x >> 5);
    if (row >= Nn) return;
    const int c = (threadIdx.x & 31) << 2;
    const int j0 = off[row], j1 = off[row + 1];
    float4 a0 = make_float4(0.f, 0.f, 0.f, 0.f);
    float4 a1 = make_float4(0.f, 0.f, 0.f, 0.f);
    int j = j0;
    for (; j + 1 < j1; j += 2) {
        const int s0 = srcidx[j];
        const int s1 = srcidx[j + 1];
        const float4 v0 = *(const float4*)&src[(size_t)s0 * 128 + c];
        const float4 v1 = *(const float4*)&src[(size_t)s1 * 128 + c];
        a0.x += v0.x; a0.y += v0.y; a0.z += v0.z; a0.w += v0.w;
        a1.x += v1.x; a1.y += v1.y; a1.z += v1.z; a1.w += v1.w;
    }
    if (j < j1) {
        const int s0 = srcidx[j];
        const float4 v0 = *(const float4*)&src[(size_t)s0 * 128 + c];
        a0.x += v0.x; a0.y += v0.y; a0.z += v0.z; a0.w += v0.w;
    }
    float4 acc = make_float4(a0.x + a1.x, a0.y + a1.y, a0.z + a1.z, a0.w + a1.w);
    if (scale) {
        const float s = scale[row];
        acc.x *= s; acc.y *= s; acc.z *= s; acc.w *= s;
    }
    *(float4*)&dst[(size_t)row * 128 + c] = acc;
}

// ---------------------------------------------------------------------------
// CSR gather, D=64: 16 lanes per row. Optional fused epilogue:
//   post_bias != null:  out = relu(scale[row]*sum + post_bias[col])
// ---------------------------------------------------------------------------
__global__ __launch_bounds__(256) void gather_rows_64(const float* __restrict__ src,
                                                      const int* __restrict__ off,
                                                      const int* __restrict__ srcidx,
                                                      const float* __restrict__ scale,
                                                      const float* __restrict__ post_bias,
                                                      float* __restrict__ dst, int Nn) {
    const int row = blockIdx.x * 16 + (threadIdx.x >> 4);
    if (row >= Nn) return;
    const int c = (threadIdx.x & 15) << 2;
    const int j0 = off[row], j1 = off[row + 1];
    float4 a0 = make_float4(0.f, 0.f, 0.f, 0.f);
    float4 a1 = make_float4(0.f, 0.f, 0.f, 0.f);
    int j = j0;
    for (; j + 1 < j1; j += 2) {
        const int s0 = srcidx[j];
        const int s1 = srcidx[j + 1];
        const float4 v0 = *(const float4*)&src[(size_t)s0 * 64 + c];
        const float4 v1 = *(const float4*)&src[(size_t)s1 * 64 + c];
        a0.x += v0.x; a0.y += v0.y; a0.z += v0.z; a0.w += v0.w;
        a1.x += v1.x; a1.y += v1.y; a1.z += v1.z; a1.w += v1.w;
    }
    if (j < j1) {
        const int s0 = srcidx[j];
        const float4 v0 = *(const float4*)&src[(size_t)s0 * 64 + c];
        a0.x += v0.x; a0.y += v0.y; a0.z += v0.z; a0.w += v0.w;
    }
    float4 acc = make_float4(a0.x + a1.x, a0.y + a1.y, a0.z + a1.z, a0.w + a1.w);
    if (scale) {
        const float s = scale[row];
        acc.x *= s; acc.y *= s; acc.z *= s; acc.w *= s;
    }
    if (post_bias) {
        acc.x = fmaxf(acc.x + post_bias[c + 0], 0.f);
        acc.y = fmaxf(acc.y + post_bias[c + 1], 0.f);
        acc.z = fmaxf(acc.z + post_bias[c + 2], 0.f);
        acc.w = fmaxf(acc.w + post_bias[c + 3], 0.f);
    }
    *(float4*)&dst[(size_t)row * 64 + c] = acc;
}

// ---------------------------------------------------------------------------
// GEMM1: C[M,256] = relu(dinv[row] * (A[M,128] @ B[128,256]) + bias[col])
// 128x128 tile, BK=32, 256 threads, 8x8 micro-tile.
// ---------------------------------------------------------------------------
__global__ __launch_bounds__(256) void gemm1_f32(const float* __restrict__ A,
                                                 const float* __restrict__ B,
                                                 float* __restrict__ C, int M,
                                                 const float* __restrict__ dinv,
                                                 const float* __restrict__ bias) {
    __shared__ float As[32][132];   // [k][m]
    __shared__ float Bs[32][128];   // [k][n]
    const int tid = threadIdx.x;
    const int m0 = blockIdx.y * 128;
    const int bn = blockIdx.x * 128;
    const int tr = (tid >> 4) << 3;   // 0..120 (4 distinct per wave -> near-broadcast)
    const int tc = (tid & 15) << 3;   // 0..120

    float acc[8][8] = {{0.f}};

    for (int k0 = 0; k0 < 128; k0 += 32) {
        // stage A transposed: 128 rows x 32 k = 1024 float4
#pragma unroll
        for (int i = 0; i < 4; i++) {
            const int f = tid + 256 * i;
            const int r = f >> 3;
            const int q = (f & 7) << 2;
            const int grow = m0 + r;
            float4 v = make_float4(0.f, 0.f, 0.f, 0.f);
            if (grow < M) v = *(const float4*)&A[(size_t)grow * 128 + k0 + q];
            As[q + 0][r] = v.x;
            As[q + 1][r] = v.y;
            As[q + 2][r] = v.z;
            As[q + 3][r] = v.w;
        }
        // stage B: 32 rows x 128 cols = 1024 float4
#pragma unroll
        for (int i = 0; i < 4; i++) {
            const int f = tid + 256 * i;
            const int r = f >> 5;
            const int c4 = (f & 31) << 2;
            *(float4*)&Bs[r][c4] = *(const float4*)&B[(size_t)(k0 + r) * 256 + bn + c4];
        }
        __syncthreads();
#pragma unroll
        for (int k = 0; k < 32; k++) {
            float av[8], bv[8];
            *(float4*)&av[0] = *(const float4*)&As[k][tr];
            *(float4*)&av[4] = *(const float4*)&As[k][tr + 4];
            *(float4*)&bv[0] = *(const float4*)&Bs[k][tc];
            *(float4*)&bv[4] = *(const float4*)&Bs[k][tc + 4];
#pragma unroll
            for (int r = 0; r < 8; r++)
#pragma unroll
                for (int c = 0; c < 8; c++)
                    acc[r][c] = fmaf(av[r], bv[c], acc[r][c]);
        }
        __syncthreads();
    }
#pragma unroll
    for (int r = 0; r < 8; r++) {
        const int grow = m0 + tr + r;
        if (grow < M) {
            const float s = dinv[grow];
            float o[8];
#pragma unroll
            for (int c = 0; c < 8; c++)
                o[c] = fmaxf(fmaf(acc[r][c], s, bias[bn + tc + c]), 0.f);
            *(float4*)&C[(size_t)grow * 256 + bn + tc] = *(float4*)&o[0];
            *(float4*)&C[(size_t)grow * 256 + bn + tc + 4] = *(float4*)&o[4];
        }
    }
}

// ---------------------------------------------------------------------------
// GEMM2: C[M,64] = A[M,256] @ B[256,64]  (plain)
// 128x64 tile, BK=32, 256 threads, 4x8 micro-tile.
// ---------------------------------------------------------------------------
__global__ __launch_bounds__(256) void gemm2_f32(const float* __restrict__ A,
                                                 const float* __restrict__ B,
                                                 float* __restrict__ C, int M) {
    __shared__ float As[32][132];   // [k][m]
    __shared__ float Bs[32][64];    // [k][n]
    const int tid = threadIdx.x;
    const int m0 = blockIdx.y * 128;
    const int tr = (tid >> 3) << 2;   // 0..124
    const int tc = (tid & 7) << 3;    // 0..56

    float acc[4][8] = {{0.f}};

    for (int k0 = 0; k0 < 256; k0 += 32) {
        // stage A transposed
#pragma unroll
        for (int i = 0; i < 4; i++) {
            const int f = tid + 256 * i;
            const int r = f >> 3;
            const int q = (f & 7) << 2;
            const int grow = m0 + r;
            float4 v = make_float4(0.f, 0.f, 0.f, 0.f);
            if (grow < M) v = *(const float4*)&A[(size_t)grow * 256 + k0 + q];
            As[q + 0][r] = v.x;
            As[q + 1][r] = v.y;
            As[q + 2][r] = v.z;
            As[q + 3][r] = v.w;
        }
        // stage B: 32 x 64 = 512 float4
#pragma unroll
        for (int i = 0; i < 2; i++) {
            const int f = tid + 256 * i;
            const int r = f >> 4;
            const int c4 = (f & 15) << 2;
            *(float4*)&Bs[r][c4] = *(const float4*)&B[(size_t)(k0 + r) * 64 + c4];
        }
        __syncthreads();
#pragma unroll
        for (int k = 0; k < 32; k++) {
            float av[4], bv[8];
            *(float4*)&av[0] = *(const float4*)&As[k][tr];
            *(float4*)&bv[0] = *(const float4*)&Bs[k][tc];
            *(float4*)&bv[4] = *(const float4*)&Bs[k][tc + 4];
#pragma unroll
            for (int r = 0; r < 4; r++)
#pragma unroll
                for (int c = 0; c < 8; c++)
                    acc[r][c] = fmaf(av[r], bv[c], acc[r][c]);
        }
        __syncthreads();
    }
#pragma unroll
    for (int r = 0; r < 4; r++) {
        const int grow = m0 + tr + r;
        if (grow < M) {
            *(float4*)&C[(size_t)grow * 64 + tc] =
                make_float4(acc[r][0], acc[r][1], acc[r][2], acc[r][3]);
            *(float4*)&C[(size_t)grow * 64 + tc + 4] =
                make_float4(acc[r][4], acc[r][5], acc[r][6], acc[r][7]);
        }
    }
}

// ---------------------------------------------------------------------------
// hyperedge embedding
// ---------------------------------------------------------------------------
__global__ __launch_bounds__(256) void hye_emb_kernel(const float* __restrict__ emb,
                                                      const int* __restrict__ hnode,
                                                      const float* __restrict__ hlen,
                                                      float* __restrict__ out, int Nn) {
    const int r = blockIdx.x * 16 + (threadIdx.x >> 4);
    const int c = (threadIdx.x & 15) << 2;
    if (r >= Nn) return;
    const int* hp = &hnode[(size_t)r * 16];
    float4 acc = make_float4(0.f, 0.f, 0.f, 0.f);
#pragma unroll
    for (int l = 0; l < 16; l++) {
        const int idx = hp[l];
        if (idx > 0) {
            const float4 v = *(const float4*)&emb[(size_t)(idx - 1) * 64 + c];
            acc.x += v.x; acc.y += v.y; acc.z += v.z; acc.w += v.w;
        }
    }
    const float inv = 1.0f / (hlen[r] + 1e-15f);
    acc.x *= inv; acc.y *= inv; acc.z *= inv; acc.w *= inv;
    *(float4*)&out[(size_t)r * 64 + c] = acc;
}

// ---------------------------------------------------------------------------
// Fusion-attention scores as tiled GEMM with fused tanh*W2 reduce epilogue.
// ---------------------------------------------------------------------------
struct AttnArgs {
    const float* z[8];
    const float* W1c; const float* b1c; const float* W2c;
    const float* W1m; const float* b1m; const float* W2m;
    float* accw;
    int Nn;
};

__global__ __launch_bounds__(256) void attn_gemm(AttnArgs a) {
    __shared__ float As[64][132];   // [k][m]
    __shared__ float Bs[64][128];   // [k][h]
    __shared__ float red[4];
    const int tid = threadIdx.x;
    const int gy = blockIdx.y;      // head*4 + comp
    const int head = gy >> 2;
    const float* __restrict__ z  = a.z[gy];
    const float* __restrict__ W1 = head ? a.W1m : a.W1c;
    const float* __restrict__ b1 = head ? a.b1m : a.b1c;
    const float* __restrict__ W2 = head ? a.W2m : a.W2c;
    const int m0 = blockIdx.x * 128;

    {
        const int c4 = tid & 15;
        const int mb = tid >> 4;
#pragma unroll
        for (int i = 0; i < 8; i++) {
            const int m = mb + 16 * i;
            const int grow = m0 + m;
            float4 v = make_float4(0.f, 0.f, 0.f, 0.f);
            if (grow < a.Nn) v = *(const float4*)&z[(size_t)grow * 64 + c4 * 4];
            As[c4 * 4 + 0][m] = v.x;
            As[c4 * 4 + 1][m] = v.y;
            As[c4 * 4 + 2][m] = v.z;
            As[c4 * 4 + 3][m] = v.w;
        }
    }
    {
#pragma unroll
        for (int i = 0; i < 8; i++) {
            const int f = tid + 256 * i;
            const int r = f >> 5, cc = (f & 31) << 2;
            *(float4*)&Bs[r][cc] = *(const float4*)&W1[(size_t)r * 128 + cc];
        }
    }
    __syncthreads();

    const int tr = (tid & 15) * 8;
    const int tc = (tid >> 4) * 8;
    float acc[8][8] = {{0.f}};
    for (int k = 0; k < 64; k++) {
        float av[8], bv[8];
        *(float4*)&av[0] = *(const float4*)&As[k][tr];
        *(float4*)&av[4] = *(const float4*)&As[k][tr + 4];
        *(float4*)&bv[0] = *(const float4*)&Bs[k][tc];
        *(float4*)&bv[4] = *(const float4*)&Bs[k][tc + 4];
#pragma unroll
        for (int r = 0; r < 8; r++)
#pragma unroll
            for (int c = 0; c < 8; c++)
                acc[r][c] = fmaf(av[r], bv[c], acc[r][c]);
    }

    float w2v[8], b1v[8];
#pragma unroll
    for (int c = 0; c < 8; c++) { w2v[c] = W2[tc + c]; b1v[c] = b1[tc + c]; }
    float local = 0.f;
#pragma unroll
    for (int r = 0; r < 8; r++) {
        if (m0 + tr + r < a.Nn) {
#pragma unroll
            for (int c = 0; c < 8; c++) {
                float s = acc[r][c] + b1v[c];
                s = fminf(fmaxf(s, -15.f), 15.f);
                const float t = __expf(2.f * s);
                local += (1.f - 2.f / (t + 1.f)) * w2v[c];
            }
        }
    }
#pragma unroll
    for (int off = 32; off >= 1; off >>= 1) local += __shfl_down(local, off, 64);
    if ((tid & 63) == 0) red[tid >> 6] = local;
    __syncthreads();
    if (tid == 0) atomicAdd(&a.accw[gy], red[0] + red[1] + red[2] + red[3]);
}

__global__ void softmax_beta(const float* __restrict__ acc, float* __restrict__ beta,
                             float invN) {
    const int t = threadIdx.x;
    if (t < 2) {
        const float* a = acc + 4 * t;
        float* b = beta + 4 * t;
        float w[4], m = -1e30f;
#pragma unroll
        for (int i = 0; i < 4; i++) { w[i] = a[i] * invN; m = fmaxf(m, w[i]); }
        float s = 0.f;
#pragma unroll
        for (int i = 0; i < 4; i++) { w[i] = expf(w[i] - m); s += w[i]; }
#pragma unroll
        for (int i = 0; i < 4; i++) b[i] = w[i] / s;
    }
}

__global__ __launch_bounds__(256) void weighted_sum(const float* __restrict__ z0,
                                                    const float* __restrict__ z1,
                                                    const float* __restrict__ z2,
                                                    const float* __restrict__ z3,
                                                    const float* __restrict__ beta,
                                                    float* __restrict__ out, int Nn) {
    const int t = blockIdx.x * 256 + threadIdx.x;
    if (t >= Nn * 16) return;
    const float b0 = beta[0], b1 = beta[1], b2 = beta[2], b3 = beta[3];
    const float4 v0 = *(const float4*)&z0[(size_t)t * 4];
    const float4 v1 = *(const float4*)&z1[(size_t)t * 4];
    const float4 v2 = *(const float4*)&z2[(size_t)t * 4];
    const float4 v3 = *(const float4*)&z3[(size_t)t * 4];
    float4 o;
    o.x = b0 * v0.x + b1 * v1.x + b2 * v2.x + b3 * v3.x;
    o.y = b0 * v0.y + b1 * v1.y + b2 * v2.y + b3 * v3.y;
    o.z = b0 * v0.z + b1 * v1.z + b2 * v2.z + b3 * v3.z;
    o.w = b0 * v0.w + b1 * v1.w + b2 * v2.w + b3 * v3.w;
    *(float4*)&out[(size_t)t * 4] = o;
}

// ---------------------------------------------------------------------------
extern "C" void kernel_launch(void* const* d_in, const int* in_sizes, int n_in,
                              void* d_out, int out_size, void* d_ws, size_t ws_size,
                              hipStream_t stream) {
    const int Nn = in_sizes[0] / NF;   // 50000
    const int E  = in_sizes[1] / 2;    // 800000
    const int N2 = 2 * Nn;

    const float* x[4];
    const int*   ei[4];
    const int*   hnode[4];
    const float* hlen[4];
    for (int g = 0; g < 4; g++) {
        x[g]     = (const float*)d_in[4 * g + 0];
        ei[g]    = (const int*)d_in[4 * g + 1];
        hnode[g] = (const int*)d_in[4 * g + 2];
        hlen[g]  = (const float*)d_in[4 * g + 3];
    }
    const float* W1   = (const float*)d_in[16];
    const float* b1   = (const float*)d_in[17];
    const float* W2   = (const float*)d_in[18];
    const float* b2   = (const float*)d_in[19];
    const float* acW1 = (const float*)d_in[20];
    const float* acb1 = (const float*)d_in[21];
    const float* acW2 = (const float*)d_in[22];
    const float* amW1 = (const float*)d_in[23];
    const float* amb1 = (const float*)d_in[24];
    const float* amW2 = (const float*)d_in[25];

    // workspace layout
    float* ws = (float*)d_ws;
    size_t o = 0;
    float* bufA = ws + o; o += (size_t)Nn * DD1;
    float* bufB = ws + o; o += (size_t)Nn * DD1;
    float* dinv = ws + o; o += N2;          // [d_inv(N) | b_inv(N)]
    float* h2[4];
    float* hemb[4];
    for (int g = 0; g < 4; g++) { h2[g]   = ws + o; o += (size_t)Nn * DD2; }
    for (int g = 0; g < 4; g++) { hemb[g] = ws + o; o += (size_t)Nn * DD2; }
    float* accw = ws + o; o += 8;
    float* beta = ws + o; o += 8;
    int* iws = (int*)(ws + o);
    size_t io = 0;
    int* deg_i    = iws + io; io += N2;
    int* off      = iws + io; io += N2 + 1;
    int* partials = iws + io; io += 256;
    int* rank     = iws + io; io += E;
    int* srcidx   = iws + io; io += (size_t)2 * E;

    const int nScanBlocks = cdiv(N2, 1024);
    const int shardSize = cdiv(Nn, 8);

    for (int g = 0; g < 4; g++) {
        const int* nidx = ei[g];
        const int* eidx = ei[g] + E;
        const int* off_n = off;        // CSR by nidx (edge -> node passes)
        const int* off_e = off + Nn;   // CSR by eidx (node -> edge passes)
        const float* d_inv = dinv;
        const float* b_inv = dinv + Nn;

        // ---- build CSRs ----
        hipMemsetAsync(deg_i, 0, (size_t)N2 * sizeof(int), stream);
        count_rank<<<cdiv(E, 256), 256, 0, stream>>>(nidx, eidx, deg_i, rank, Nn, E);
        scan_blocks<<<nScanBlocks, 256, 0, stream>>>(deg_i, off, partials, N2);
        scan_partials<<<1, 256, 0, stream>>>(partials, nScanBlocks);
        scan_add<<<cdiv(N2, 256), 256, 0, stream>>>(off, partials, N2, 2 * E);
        build_fill<<<8 * cdiv(E, 1024), 256, 0, stream>>>(nidx, eidx, rank, off,
                                                          srcidx, Nn, E, shardSize);
        invert_deg_int<<<cdiv(N2, 256), 256, 0, stream>>>(deg_i, dinv, N2);

        // ---- hconv1 (W1 commuted past segment-sums) ----
        // G = b_inv * segsum_e(x)  [Nn,128]
        gather_rows_128<<<cdiv(Nn, 8), 256, 0, stream>>>(x[g], off_e, srcidx, b_inv, bufB, Nn);
        // G2 = segsum_n(G)  [Nn,128]
        gather_rows_128<<<cdiv(Nn, 8), 256, 0, stream>>>(bufB, off_n, srcidx, nullptr, bufA, Nn);
        // x1 = relu(d_inv*(G2 @ W1) + b1)  [Nn,256]
        gemm1_f32<<<dim3(2, cdiv(Nn, 128)), 256, 0, stream>>>(bufA, W1, bufB, Nn, d_inv, b1);

        // ---- hconv2 ----
        // x2lin = x1 @ W2  [Nn,64]
        gemm2_f32<<<dim3(1, cdiv(Nn, 128)), 256, 0, stream>>>(bufB, W2, bufA, Nn);
        gather_rows_64<<<cdiv(Nn, 16), 256, 0, stream>>>(bufA, off_e, srcidx, b_inv,
                                                         nullptr, bufB, Nn);
        gather_rows_64<<<cdiv(Nn, 16), 256, 0, stream>>>(bufB, off_n, srcidx, d_inv,
                                                         b2, h2[g], Nn);

        // hyperedge embedding
        hye_emb_kernel<<<cdiv(Nn, 16), 256, 0, stream>>>(h2[g], hnode[g], hlen[g], hemb[g], Nn);
    }

    // ---- fusion attention ----
    hipMemsetAsync(accw, 0, 8 * sizeof(float), stream);
    AttnArgs aa;
    aa.z[0] = h2[1]; aa.z[1] = hemb[0]; aa.z[2] = h2[2]; aa.z[3] = hemb[2];
    aa.z[4] = h2[0]; aa.z[5] = hemb[1]; aa.z[6] = h2[3]; aa.z[7] = hemb[3];
    aa.W1c = acW1; aa.b1c = acb1; aa.W2c = acW2;
    aa.W1m = amW1; aa.b1m = amb1; aa.W2m = amW2;
    aa.accw = accw; aa.Nn = Nn;
    attn_gemm<<<dim3(cdiv(Nn, 128), 8), 256, 0, stream>>>(aa);
    softmax_beta<<<1, 64, 0, stream>>>(accw, beta, 1.0f / (float)Nn);

    float* out = (float*)d_out;
    weighted_sum<<<cdiv(Nn * 16, 256), 256, 0, stream>>>(h2[1], hemb[0], h2[2], hemb[2],
                                                         beta + 0, out, Nn);
    weighted_sum<<<cdiv(Nn * 16, 256), 256, 0, stream>>>(h2[0], hemb[1], h2[3], hemb[3],
                                                         beta + 4, out + (size_t)Nn * DD2, Nn);
}

// Round 5
// 1883.140 us; speedup vs baseline: 14.9733x; 1.0117x over previous
//
#include <hip/hip_runtime.h>
#include <hip/hip_bf16.h>

// Problem constants
#define NF   128   // in_channels
#define DD1  256   // dim_1
#define DD2  64    // dim_1/4
#define HATT 128   // attention hidden

static inline int cdiv(int a, int b) { return (a + b - 1) / b; }

// ---------------------------------------------------------------------------
// Pass 1: degree count + per-edge rank capture (rank < 2^16 since max deg ~45).
// rank[e] = rank_within_node_list | (rank_within_edge_list << 16)
// ---------------------------------------------------------------------------
__global__ __launch_bounds__(256) void count_rank(const int* __restrict__ nidx,
                                                  const int* __restrict__ eidx,
                                                  int* __restrict__ deg,
                                                  int* __restrict__ rank,
                                                  int N, int E) {
    int e = blockIdx.x * 256 + threadIdx.x;
    if (e < E) {
        const int vn = nidx[e], ve = eidx[e];
        const int rn = atomicAdd(&deg[vn], 1);
        const int re = atomicAdd(&deg[N + ve], 1);
        rank[e] = rn | (re << 16);
    }
}

// block = 256 threads, 4 elems/thread -> 1024 elems/block
__global__ __launch_bounds__(256) void scan_blocks(const int* __restrict__ in,
                                                   int* __restrict__ out,
                                                   int* __restrict__ partials, int n) {
    __shared__ int s[256];
    const int base = blockIdx.x * 1024;
    const int t = threadIdx.x;
    int v[4], sum = 0;
#pragma unroll
    for (int i = 0; i < 4; i++) {
        const int idx = base + t * 4 + i;
        v[i] = (idx < n) ? in[idx] : 0;
        sum += v[i];
    }
    s[t] = sum;
    __syncthreads();
    for (int o = 1; o < 256; o <<= 1) {
        int x = 0;
        if (t >= o) x = s[t - o];
        __syncthreads();
        if (t >= o) s[t] += x;
        __syncthreads();
    }
    if (t == 255) partials[blockIdx.x] = s[255];
    int run = (t == 0) ? 0 : s[t - 1];
#pragma unroll
    for (int i = 0; i < 4; i++) {
        const int idx = base + t * 4 + i;
        if (idx < n) out[idx] = run;
        run += v[i];
    }
}

__global__ __launch_bounds__(256) void scan_partials(int* __restrict__ partials, int P) {
    __shared__ int s[256];
    const int t = threadIdx.x;
    s[t] = (t < P) ? partials[t] : 0;
    __syncthreads();
    for (int o = 1; o < 256; o <<= 1) {
        int x = 0;
        if (t >= o) x = s[t - o];
        __syncthreads();
        if (t >= o) s[t] += x;
        __syncthreads();
    }
    if (t < P) partials[t] = (t == 0) ? 0 : s[t - 1];
}

__global__ __launch_bounds__(256) void scan_add(int* __restrict__ off,
                                                const int* __restrict__ partials,
                                                int n, int total) {
    const int idx = blockIdx.x * 256 + threadIdx.x;
    if (idx < n) off[idx] += partials[idx >> 10];
    if (idx == 0) off[n] = total;
}

// ---------------------------------------------------------------------------
// Pass 2: store-only CSR fill, sharded by destination-vertex range.
// ---------------------------------------------------------------------------
__global__ __launch_bounds__(256) void build_fill(const int* __restrict__ nidx,
                                                  const int* __restrict__ eidx,
                                                  const int* __restrict__ rank,
                                                  const int* __restrict__ off,
                                                  int* __restrict__ srcidx,
                                                  int N, int E, int shardSize) {
    const int shard = blockIdx.x & 7;
    const int chunk = blockIdx.x >> 3;
    const int lo = shard * shardSize;
    const int hi = lo + shardSize;
    const int base = chunk * 1024;
#pragma unroll
    for (int i = 0; i < 4; i++) {
        const int e = base + i * 256 + threadIdx.x;
        if (e < E) {
            const int vn = nidx[e], ve = eidx[e];
            const int rk = rank[e];
            if (vn >= lo && vn < hi)
                srcidx[off[vn] + (rk & 0xffff)] = ve;
            if (ve >= lo && ve < hi)
                srcidx[off[N + ve] + (rk >> 16)] = vn;
        }
    }
}

__global__ __launch_bounds__(256) void invert_deg_int(const int* __restrict__ deg,
                                                      float* __restrict__ inv, int n) {
    int t = blockIdx.x * 256 + threadIdx.x;
    if (t < n) {
        const int v = deg[t];
        inv[t] = (v > 0) ? 1.0f / (float)v : 0.f;
    }
}

// ---------------------------------------------------------------------------
// CSR gather, D=128: 32 lanes per row, 8 rows per block. Unroll 4, 4 accs.
// ---------------------------------------------------------------------------
__global__ __launch_bounds__(256) void gather_rows_128(const float* __restrict__ src,
                                                       const int* __restrict__ off,
                                                       const int* __restrict__ srcidx,
                                                       const float* __restrict__ scale,
                                                       float* __restrict__ dst, int Nn) {
    const int row = blockIdx.x * 8 + (threadIdx.x >> 5);
    if (row >= Nn) return;
    const int c = (threadIdx.x & 31) << 2;
    const int j0 = off[row], j1 = off[row + 1];
    float4 a0 = make_float4(0.f, 0.f, 0.f, 0.f);
    float4 a1 = make_float4(0.f, 0.f, 0.f, 0.f);
    float4 a2 = make_float4(0.f, 0.f, 0.f, 0.f);
    float4 a3 = make_float4(0.f, 0.f, 0.f, 0.f);
    int j = j0;
    for (; j + 3 < j1; j += 4) {
        const int s0 = srcidx[j + 0];
        const int s1 = srcidx[j + 1];
        const int s2 = srcidx[j + 2];
        const int s3 = srcidx[j + 3];
        const float4 v0 = *(const float4*)&src[(size_t)s0 * 128 + c];
        const float4 v1 = *(const float4*)&src[(size_t)s1 * 128 + c];
        const float4 v2 = *(const float4*)&src[(size_t)s2 * 128 + c];
        const float4 v3 = *(const float4*)&src[(size_t)s3 * 128 + c];
        a0.x += v0.x; a0.y += v0.y; a0.z += v0.z; a0.w += v0.w;
        a1.x += v1.x; a1.y += v1.y; a1.z += v1.z; a1.w += v1.w;
        a2.x += v2.x; a2.y += v2.y; a2.z += v2.z; a2.w += v2.w;
        a3.x += v3.x; a3.y += v3.y; a3.z += v3.z; a3.w += v3.w;
    }
    for (; j < j1; j++) {
        const int s0 = srcidx[j];
        const float4 v0 = *(const float4*)&src[(size_t)s0 * 128 + c];
        a0.x += v0.x; a0.y += v0.y; a0.z += v0.z; a0.w += v0.w;
    }
    float4 acc = make_float4(a0.x + a1.x + a2.x + a3.x, a0.y + a1.y + a2.y + a3.y,
                             a0.z + a1.z + a2.z + a3.z, a0.w + a1.w + a2.w + a3.w);
    if (scale) {
        const float s = scale[row];
        acc.x *= s; acc.y *= s; acc.z *= s; acc.w *= s;
    }
    *(float4*)&dst[(size_t)row * 128 + c] = acc;
}

// ---------------------------------------------------------------------------
// CSR gather, D=64: 16 lanes per row. Unroll 4. Optional fused epilogue.
// ---------------------------------------------------------------------------
__global__ __launch_bounds__(256) void gather_rows_64(const float* __restrict__ src,
                                                      const int* __restrict__ off,
                                                      const int* __restrict__ srcidx,
                                                      const float* __restrict__ scale,
                                                      const float* __restrict__ post_bias,
                                                      float* __restrict__ dst, int Nn) {
    const int row = blockIdx.x * 16 + (threadIdx.x >> 4);
    if (row >= Nn) return;
    const int c = (threadIdx.x & 15) << 2;
    const int j0 = off[row], j1 = off[row + 1];
    float4 a0 = make_float4(0.f, 0.f, 0.f, 0.f);
    float4 a1 = make_float4(0.f, 0.f, 0.f, 0.f);
    float4 a2 = make_float4(0.f, 0.f, 0.f, 0.f);
    float4 a3 = make_float4(0.f, 0.f, 0.f, 0.f);
    int j = j0;
    for (; j + 3 < j1; j += 4) {
        const int s0 = srcidx[j + 0];
        const int s1 = srcidx[j + 1];
        const int s2 = srcidx[j + 2];
        const int s3 = srcidx[j + 3];
        const float4 v0 = *(const float4*)&src[(size_t)s0 * 64 + c];
        const float4 v1 = *(const float4*)&src[(size_t)s1 * 64 + c];
        const float4 v2 = *(const float4*)&src[(size_t)s2 * 64 + c];
        const float4 v3 = *(const float4*)&src[(size_t)s3 * 64 + c];
        a0.x += v0.x; a0.y += v0.y; a0.z += v0.z; a0.w += v0.w;
        a1.x += v1.x; a1.y += v1.y; a1.z += v1.z; a1.w += v1.w;
        a2.x += v2.x; a2.y += v2.y; a2.z += v2.z; a2.w += v2.w;
        a3.x += v3.x; a3.y += v3.y; a3.z += v3.z; a3.w += v3.w;
    }
    for (; j < j1; j++) {
        const int s0 = srcidx[j];
        const float4 v0 = *(const float4*)&src[(size_t)s0 * 64 + c];
        a0.x += v0.x; a0.y += v0.y; a0.z += v0.z; a0.w += v0.w;
    }
    float4 acc = make_float4(a0.x + a1.x + a2.x + a3.x, a0.y + a1.y + a2.y + a3.y,
                             a0.z + a1.z + a2.z + a3.z, a0.w + a1.w + a2.w + a3.w);
    if (scale) {
        const float s = scale[row];
        acc.x *= s; acc.y *= s; acc.z *= s; acc.w *= s;
    }
    if (post_bias) {
        acc.x = fmaxf(acc.x + post_bias[c + 0], 0.f);
        acc.y = fmaxf(acc.y + post_bias[c + 1], 0.f);
        acc.z = fmaxf(acc.z + post_bias[c + 2], 0.f);
        acc.w = fmaxf(acc.w + post_bias[c + 3], 0.f);
    }
    *(float4*)&dst[(size_t)row * 64 + c] = acc;
}

// ---------------------------------------------------------------------------
// GEMM1: C[M,256] = relu(dinv[row] * (A[M,128] @ B[128,256]) + bias[col])
// 128x128 tile, BK=32. Split-half micro-tile: thread covers rows
// rq..rq+3 & 64+rq.., cols cq..cq+3 & 64+cq.. -> 16B lane stride in LDS
// (2-way bank aliasing = free; old stride-32B mapping was 4-way).
// ---------------------------------------------------------------------------
__global__ __launch_bounds__(256) void gemm1_f32(const float* __restrict__ A,
                                                 const float* __restrict__ B,
                                                 float* __restrict__ C, int M,
                                                 const float* __restrict__ dinv,
                                                 const float* __restrict__ bias) {
    __shared__ float As[32][132];   // [k][m]
    __shared__ float Bs[32][128];   // [k][n]
    const int tid = threadIdx.x;
    const int m0 = blockIdx.y * 128;
    const int bn = blockIdx.x * 128;
    const int rq = (tid >> 4) << 2;   // 0..60
    const int cq = (tid & 15) << 2;   // 0..60

    float acc[8][8] = {{0.f}};

    for (int k0 = 0; k0 < 128; k0 += 32) {
#pragma unroll
        for (int i = 0; i < 4; i++) {
            const int f = tid + 256 * i;
            const int r = f >> 3;
            const int q = (f & 7) << 2;
            const int grow = m0 + r;
            float4 v = make_float4(0.f, 0.f, 0.f, 0.f);
            if (grow < M) v = *(const float4*)&A[(size_t)grow * 128 + k0 + q];
            As[q + 0][r] = v.x;
            As[q + 1][r] = v.y;
            As[q + 2][r] = v.z;
            As[q + 3][r] = v.w;
        }
#pragma unroll
        for (int i = 0; i < 4; i++) {
            const int f = tid + 256 * i;
            const int r = f >> 5;
            const int c4 = (f & 31) << 2;
            *(float4*)&Bs[r][c4] = *(const float4*)&B[(size_t)(k0 + r) * 256 + bn + c4];
        }
        __syncthreads();
#pragma unroll
        for (int k = 0; k < 32; k++) {
            float av[8], bv[8];
            *(float4*)&av[0] = *(const float4*)&As[k][rq];
            *(float4*)&av[4] = *(const float4*)&As[k][rq + 64];
            *(float4*)&bv[0] = *(const float4*)&Bs[k][cq];
            *(float4*)&bv[4] = *(const float4*)&Bs[k][cq + 64];
#pragma unroll
            for (int r = 0; r < 8; r++)
#pragma unroll
                for (int c = 0; c < 8; c++)
                    acc[r][c] = fmaf(av[r], bv[c], acc[r][c]);
        }
        __syncthreads();
    }
#pragma unroll
    for (int r = 0; r < 8; r++) {
        const int grow = m0 + rq + (r & 3) + ((r >> 2) << 6);
        if (grow < M) {
            const float s = dinv[grow];
            float o[8];
#pragma unroll
            for (int c = 0; c < 4; c++)
                o[c] = fmaxf(fmaf(acc[r][c], s, bias[bn + cq + c]), 0.f);
#pragma unroll
            for (int c = 4; c < 8; c++)
                o[c] = fmaxf(fmaf(acc[r][c], s, bias[bn + 64 + cq + (c - 4)]), 0.f);
            *(float4*)&C[(size_t)grow * 256 + bn + cq] = *(float4*)&o[0];
            *(float4*)&C[(size_t)grow * 256 + bn + 64 + cq] = *(float4*)&o[4];
        }
    }
}

// ---------------------------------------------------------------------------
// GEMM2: C[M,64] = A[M,256] @ B[256,64]  (plain)
// 128x64 tile, BK=32, 4x8 micro-tile (lane strides already conflict-free).
// ---------------------------------------------------------------------------
__global__ __launch_bounds__(256) void gemm2_f32(const float* __restrict__ A,
                                                 const float* __restrict__ B,
                                                 float* __restrict__ C, int M) {
    __shared__ float As[32][132];   // [k][m]
    __shared__ float Bs[32][64];    // [k][n]
    const int tid = threadIdx.x;
    const int m0 = blockIdx.y * 128;
    const int tr = (tid >> 3) << 2;   // 0..124, 16B lane stride
    const int tc = (tid & 7) << 3;    // 0..56

    float acc[4][8] = {{0.f}};

    for (int k0 = 0; k0 < 256; k0 += 32) {
#pragma unroll
        for (int i = 0; i < 4; i++) {
            const int f = tid + 256 * i;
            const int r = f >> 3;
            const int q = (f & 7) << 2;
            const int grow = m0 + r;
            float4 v = make_float4(0.f, 0.f, 0.f, 0.f);
            if (grow < M) v = *(const float4*)&A[(size_t)grow * 256 + k0 + q];
            As[q + 0][r] = v.x;
            As[q + 1][r] = v.y;
            As[q + 2][r] = v.z;
            As[q + 3][r] = v.w;
        }
#pragma unroll
        for (int i = 0; i < 2; i++) {
            const int f = tid + 256 * i;
            const int r = f >> 4;
            const int c4 = (f & 15) << 2;
            *(float4*)&Bs[r][c4] = *(const float4*)&B[(size_t)(k0 + r) * 64 + c4];
        }
        __syncthreads();
#pragma unroll
        for (int k = 0; k < 32; k++) {
            float av[4], bv[8];
            *(float4*)&av[0] = *(const float4*)&As[k][tr];
            *(float4*)&bv[0] = *(const float4*)&Bs[k][tc];
            *(float4*)&bv[4] = *(const float4*)&Bs[k][tc + 4];
#pragma unroll
            for (int r = 0; r < 4; r++)
#pragma unroll
                for (int c = 0; c < 8; c++)
                    acc[r][c] = fmaf(av[r], bv[c], acc[r][c]);
        }
        __syncthreads();
    }
#pragma unroll
    for (int r = 0; r < 4; r++) {
        const int grow = m0 + tr + r;
        if (grow < M) {
            *(float4*)&C[(size_t)grow * 64 + tc] =
                make_float4(acc[r][0], acc[r][1], acc[r][2], acc[r][3]);
            *(float4*)&C[(size_t)grow * 64 + tc + 4] =
                make_float4(acc[r][4], acc[r][5], acc[r][6], acc[r][7]);
        }
    }
}

// ---------------------------------------------------------------------------
// hyperedge embedding: split accumulate chain in two for ILP
// ---------------------------------------------------------------------------
__global__ __launch_bounds__(256) void hye_emb_kernel(const float* __restrict__ emb,
                                                      const int* __restrict__ hnode,
                                                      const float* __restrict__ hlen,
                                                      float* __restrict__ out, int Nn) {
    const int r = blockIdx.x * 16 + (threadIdx.x >> 4);
    const int c = (threadIdx.x & 15) << 2;
    if (r >= Nn) return;
    const int* hp = &hnode[(size_t)r * 16];
    float4 a0 = make_float4(0.f, 0.f, 0.f, 0.f);
    float4 a1 = make_float4(0.f, 0.f, 0.f, 0.f);
#pragma unroll
    for (int l = 0; l < 16; l += 2) {
        const int i0 = hp[l], i1 = hp[l + 1];
        if (i0 > 0) {
            const float4 v = *(const float4*)&emb[(size_t)(i0 - 1) * 64 + c];
            a0.x += v.x; a0.y += v.y; a0.z += v.z; a0.w += v.w;
        }
        if (i1 > 0) {
            const float4 v = *(const float4*)&emb[(size_t)(i1 - 1) * 64 + c];
            a1.x += v.x; a1.y += v.y; a1.z += v.z; a1.w += v.w;
        }
    }
    const float inv = 1.0f / (hlen[r] + 1e-15f);
    float4 acc;
    acc.x = (a0.x + a1.x) * inv;
    acc.y = (a0.y + a1.y) * inv;
    acc.z = (a0.z + a1.z) * inv;
    acc.w = (a0.w + a1.w) * inv;
    *(float4*)&out[(size_t)r * 64 + c] = acc;
}

// ---------------------------------------------------------------------------
// Fusion-attention scores as tiled GEMM with fused tanh*W2 reduce epilogue.
// Split-half micro-tile (16B lane stride -> conflict-free LDS reads).
// ---------------------------------------------------------------------------
struct AttnArgs {
    const float* z[8];
    const float* W1c; const float* b1c; const float* W2c;
    const float* W1m; const float* b1m; const float* W2m;
    float* accw;
    int Nn;
};

__global__ __launch_bounds__(256) void attn_gemm(AttnArgs a) {
    __shared__ float As[64][132];   // [k][m]
    __shared__ float Bs[64][128];   // [k][h]
    __shared__ float red[4];
    const int tid = threadIdx.x;
    const int gy = blockIdx.y;      // head*4 + comp
    const int head = gy >> 2;
    const float* __restrict__ z  = a.z[gy];
    const float* __restrict__ W1 = head ? a.W1m : a.W1c;
    const float* __restrict__ b1 = head ? a.b1m : a.b1c;
    const float* __restrict__ W2 = head ? a.W2m : a.W2c;
    const int m0 = blockIdx.x * 128;

    {
        const int c4 = tid & 15;
        const int mb = tid >> 4;
#pragma unroll
        for (int i = 0; i < 8; i++) {
            const int m = mb + 16 * i;
            const int grow = m0 + m;
            float4 v = make_float4(0.f, 0.f, 0.f, 0.f);
            if (grow < a.Nn) v = *(const float4*)&z[(size_t)grow * 64 + c4 * 4];
            As[c4 * 4 + 0][m] = v.x;
            As[c4 * 4 + 1][m] = v.y;
            As[c4 * 4 + 2][m] = v.z;
            As[c4 * 4 + 3][m] = v.w;
        }
    }
    {
#pragma unroll
        for (int i = 0; i < 8; i++) {
            const int f = tid + 256 * i;
            const int r = f >> 5, cc = (f & 31) << 2;
            *(float4*)&Bs[r][cc] = *(const float4*)&W1[(size_t)r * 128 + cc];
        }
    }
    __syncthreads();

    const int mq = (tid & 15) << 2;   // row quad base
    const int hq = (tid >> 4) << 2;   // col quad base
    float acc[8][8] = {{0.f}};
    for (int k = 0; k < 64; k++) {
        float av[8], bv[8];
        *(float4*)&av[0] = *(const float4*)&As[k][mq];
        *(float4*)&av[4] = *(const float4*)&As[k][mq + 64];
        *(float4*)&bv[0] = *(const float4*)&Bs[k][hq];
        *(float4*)&bv[4] = *(const float4*)&Bs[k][hq + 64];
#pragma unroll
        for (int r = 0; r < 8; r++)
#pragma unroll
            for (int c = 0; c < 8; c++)
                acc[r][c] = fmaf(av[r], bv[c], acc[r][c]);
    }

    float w2v[8], b1v[8];
#pragma unroll
    for (int c = 0; c < 8; c++) {
        const int col = hq + (c & 3) + ((c >> 2) << 6);
        w2v[c] = W2[col];
        b1v[c] = b1[col];
    }
    float local = 0.f;
#pragma unroll
    for (int r = 0; r < 8; r++) {
        const int row = m0 + mq + (r & 3) + ((r >> 2) << 6);
        if (row < a.Nn) {
#pragma unroll
            for (int c = 0; c < 8; c++) {
                float s = acc[r][c] + b1v[c];
                s = fminf(fmaxf(s, -15.f), 15.f);
                const float t = __expf(2.f * s);
                local += (1.f - 2.f / (t + 1.f)) * w2v[c];
            }
        }
    }
#pragma unroll
    for (int off = 32; off >= 1; off >>= 1) local += __shfl_down(local, off, 64);
    if ((tid & 63) == 0) red[tid >> 6] = local;
    __syncthreads();
    if (tid == 0) atomicAdd(&a.accw[gy], red[0] + red[1] + red[2] + red[3]);
}

__global__ void softmax_beta(const float* __restrict__ acc, float* __restrict__ beta,
                             float invN) {
    const int t = threadIdx.x;
    if (t < 2) {
        const float* a = acc + 4 * t;
        float* b = beta + 4 * t;
        float w[4], m = -1e30f;
#pragma unroll
        for (int i = 0; i < 4; i++) { w[i] = a[i] * invN; m = fmaxf(m, w[i]); }
        float s = 0.f;
#pragma unroll
        for (int i = 0; i < 4; i++) { w[i] = expf(w[i] - m); s += w[i]; }
#pragma unroll
        for (int i = 0; i < 4; i++) b[i] = w[i] / s;
    }
}

__global__ __launch_bounds__(256) void weighted_sum(const float* __restrict__ z0,
                                                    const float* __restrict__ z1,
                                                    const float* __restrict__ z2,
                                                    const float* __restrict__ z3,
                                                    const float* __restrict__ beta,
                                                    float* __restrict__ out, int Nn) {
    const int t = blockIdx.x * 256 + threadIdx.x;
    if (t >= Nn * 16) return;
    const float b0 = beta[0], b1 = beta[1], b2 = beta[2], b3 = beta[3];
    const float4 v0 = *(const float4*)&z0[(size_t)t * 4];
    const float4 v1 = *(const float4*)&z1[(size_t)t * 4];
    const float4 v2 = *(const float4*)&z2[(size_t)t * 4];
    const float4 v3 = *(const float4*)&z3[(size_t)t * 4];
    float4 o;
    o.x = b0 * v0.x + b1 * v1.x + b2 * v2.x + b3 * v3.x;
    o.y = b0 * v0.y + b1 * v1.y + b2 * v2.y + b3 * v3.y;
    o.z = b0 * v0.z + b1 * v1.z + b2 * v2.z + b3 * v3.z;
    o.w = b0 * v0.w + b1 * v1.w + b2 * v2.w + b3 * v3.w;
    *(float4*)&out[(size_t)t * 4] = o;
}

// ---------------------------------------------------------------------------
extern "C" void kernel_launch(void* const* d_in, const int* in_sizes, int n_in,
                              void* d_out, int out_size, void* d_ws, size_t ws_size,
                              hipStream_t stream) {
    const int Nn = in_sizes[0] / NF;   // 50000
    const int E  = in_sizes[1] / 2;    // 800000
    const int N2 = 2 * Nn;

    const float* x[4];
    const int*   ei[4];
    const int*   hnode[4];
    const float* hlen[4];
    for (int g = 0; g < 4; g++) {
        x[g]     = (const float*)d_in[4 * g + 0];
        ei[g]    = (const int*)d_in[4 * g + 1];
        hnode[g] = (const int*)d_in[4 * g + 2];
        hlen[g]  = (const float*)d_in[4 * g + 3];
    }
    const float* W1   = (const float*)d_in[16];
    const float* b1   = (const float*)d_in[17];
    const float* W2   = (const float*)d_in[18];
    const float* b2   = (const float*)d_in[19];
    const float* acW1 = (const float*)d_in[20];
    const float* acb1 = (const float*)d_in[21];
    const float* acW2 = (const float*)d_in[22];
    const float* amW1 = (const float*)d_in[23];
    const float* amb1 = (const float*)d_in[24];
    const float* amW2 = (const float*)d_in[25];

    // workspace layout
    float* ws = (float*)d_ws;
    size_t o = 0;
    float* bufA = ws + o; o += (size_t)Nn * DD1;
    float* bufB = ws + o; o += (size_t)Nn * DD1;
    float* dinv = ws + o; o += N2;          // [d_inv(N) | b_inv(N)]
    float* h2[4];
    float* hemb[4];
    for (int g = 0; g < 4; g++) { h2[g]   = ws + o; o += (size_t)Nn * DD2; }
    for (int g = 0; g < 4; g++) { hemb[g] = ws + o; o += (size_t)Nn * DD2; }
    float* accw = ws + o; o += 8;
    float* beta = ws + o; o += 8;
    int* iws = (int*)(ws + o);
    size_t io = 0;
    int* deg_i    = iws + io; io += N2;
    int* off      = iws + io; io += N2 + 1;
    int* partials = iws + io; io += 256;
    int* rank     = iws + io; io += E;
    int* srcidx   = iws + io; io += (size_t)2 * E;

    const int nScanBlocks = cdiv(N2, 1024);
    const int shardSize = cdiv(Nn, 8);

    for (int g = 0; g < 4; g++) {
        const int* nidx = ei[g];
        const int* eidx = ei[g] + E;
        const int* off_n = off;        // CSR by nidx (edge -> node passes)
        const int* off_e = off + Nn;   // CSR by eidx (node -> edge passes)
        const float* d_inv = dinv;
        const float* b_inv = dinv + Nn;

        // ---- build CSRs ----
        hipMemsetAsync(deg_i, 0, (size_t)N2 * sizeof(int), stream);
        count_rank<<<cdiv(E, 256), 256, 0, stream>>>(nidx, eidx, deg_i, rank, Nn, E);
        scan_blocks<<<nScanBlocks, 256, 0, stream>>>(deg_i, off, partials, N2);
        scan_partials<<<1, 256, 0, stream>>>(partials, nScanBlocks);
        scan_add<<<cdiv(N2, 256), 256, 0, stream>>>(off, partials, N2, 2 * E);
        build_fill<<<8 * cdiv(E, 1024), 256, 0, stream>>>(nidx, eidx, rank, off,
                                                          srcidx, Nn, E, shardSize);
        invert_deg_int<<<cdiv(N2, 256), 256, 0, stream>>>(deg_i, dinv, N2);

        // ---- hconv1 (W1 commuted past segment-sums) ----
        gather_rows_128<<<cdiv(Nn, 8), 256, 0, stream>>>(x[g], off_e, srcidx, b_inv, bufB, Nn);
        gather_rows_128<<<cdiv(Nn, 8), 256, 0, stream>>>(bufB, off_n, srcidx, nullptr, bufA, Nn);
        gemm1_f32<<<dim3(2, cdiv(Nn, 128)), 256, 0, stream>>>(bufA, W1, bufB, Nn, d_inv, b1);

        // ---- hconv2 ----
        gemm2_f32<<<dim3(1, cdiv(Nn, 128)), 256, 0, stream>>>(bufB, W2, bufA, Nn);
        gather_rows_64<<<cdiv(Nn, 16), 256, 0, stream>>>(bufA, off_e, srcidx, b_inv,
                                                         nullptr, bufB, Nn);
        gather_rows_64<<<cdiv(Nn, 16), 256, 0, stream>>>(bufB, off_n, srcidx, d_inv,
                                                         b2, h2[g], Nn);

        // hyperedge embedding
        hye_emb_kernel<<<cdiv(Nn, 16), 256, 0, stream>>>(h2[g], hnode[g], hlen[g], hemb[g], Nn);
    }

    // ---- fusion attention ----
    hipMemsetAsync(accw, 0, 8 * sizeof(float), stream);
    AttnArgs aa;
    aa.z[0] = h2[1]; aa.z[1] = hemb[0]; aa.z[2] = h2[2]; aa.z[3] = hemb[2];
    aa.z[4] = h2[0]; aa.z[5] = hemb[1]; aa.z[6] = h2[3]; aa.z[7] = hemb[3];
    aa.W1c = acW1; aa.b1c = acb1; aa.W2c = acW2;
    aa.W1m = amW1; aa.b1m = amb1; aa.W2m = amW2;
    aa.accw = accw; aa.Nn = Nn;
    attn_gemm<<<dim3(cdiv(Nn, 128), 8), 256, 0, stream>>>(aa);
    softmax_beta<<<1, 64, 0, stream>>>(accw, beta, 1.0f / (float)Nn);

    float* out = (float*)d_out;
    weighted_sum<<<cdiv(Nn * 16, 256), 256, 0, stream>>>(h2[1], hemb[0], h2[2], hemb[2],
                                                         beta + 0, out, Nn);
    weighted_sum<<<cdiv(Nn * 16, 256), 256, 0, stream>>>(h2[0], hemb[1], h2[3], hemb[3],
                                                         beta + 4, out + (size_t)Nn * DD2, Nn);
}

// Round 6
// 1866.877 us; speedup vs baseline: 15.1037x; 1.0087x over previous
//
#include <hip/hip_runtime.h>
#include <hip/hip_bf16.h>

// Problem constants
#define NF   128   // in_channels
#define DD1  256   // dim_1
#define DD2  64    // dim_1/4
#define HATT 128   // attention hidden

static inline int cdiv(int a, int b) { return (a + b - 1) / b; }

// ---------------------------------------------------------------------------
// Pass 1: degree count + per-edge rank capture (rank < 2^16 since max deg ~45).
// ---------------------------------------------------------------------------
__global__ __launch_bounds__(256) void count_rank(const int* __restrict__ nidx,
                                                  const int* __restrict__ eidx,
                                                  int* __restrict__ deg,
                                                  int* __restrict__ rank,
                                                  int N, int E) {
    int e = blockIdx.x * 256 + threadIdx.x;
    if (e < E) {
        const int vn = nidx[e], ve = eidx[e];
        const int rn = atomicAdd(&deg[vn], 1);
        const int re = atomicAdd(&deg[N + ve], 1);
        rank[e] = rn | (re << 16);
    }
}

__global__ __launch_bounds__(256) void scan_blocks(const int* __restrict__ in,
                                                   int* __restrict__ out,
                                                   int* __restrict__ partials, int n) {
    __shared__ int s[256];
    const int base = blockIdx.x * 1024;
    const int t = threadIdx.x;
    int v[4], sum = 0;
#pragma unroll
    for (int i = 0; i < 4; i++) {
        const int idx = base + t * 4 + i;
        v[i] = (idx < n) ? in[idx] : 0;
        sum += v[i];
    }
    s[t] = sum;
    __syncthreads();
    for (int o = 1; o < 256; o <<= 1) {
        int x = 0;
        if (t >= o) x = s[t - o];
        __syncthreads();
        if (t >= o) s[t] += x;
        __syncthreads();
    }
    if (t == 255) partials[blockIdx.x] = s[255];
    int run = (t == 0) ? 0 : s[t - 1];
#pragma unroll
    for (int i = 0; i < 4; i++) {
        const int idx = base + t * 4 + i;
        if (idx < n) out[idx] = run;
        run += v[i];
    }
}

__global__ __launch_bounds__(256) void scan_partials(int* __restrict__ partials, int P) {
    __shared__ int s[256];
    const int t = threadIdx.x;
    s[t] = (t < P) ? partials[t] : 0;
    __syncthreads();
    for (int o = 1; o < 256; o <<= 1) {
        int x = 0;
        if (t >= o) x = s[t - o];
        __syncthreads();
        if (t >= o) s[t] += x;
        __syncthreads();
    }
    if (t < P) partials[t] = (t == 0) ? 0 : s[t - 1];
}

__global__ __launch_bounds__(256) void scan_add(int* __restrict__ off,
                                                const int* __restrict__ partials,
                                                int n, int total) {
    const int idx = blockIdx.x * 256 + threadIdx.x;
    if (idx < n) off[idx] += partials[idx >> 10];
    if (idx == 0) off[n] = total;
}

// ---------------------------------------------------------------------------
// Pass 2: store-only CSR fill, sharded by destination-vertex range.
// ---------------------------------------------------------------------------
__global__ __launch_bounds__(256) void build_fill(const int* __restrict__ nidx,
                                                  const int* __restrict__ eidx,
                                                  const int* __restrict__ rank,
                                                  const int* __restrict__ off,
                                                  int* __restrict__ srcidx,
                                                  int N, int E, int shardSize) {
    const int shard = blockIdx.x & 7;
    const int chunk = blockIdx.x >> 3;
    const int lo = shard * shardSize;
    const int hi = lo + shardSize;
    const int base = chunk * 1024;
#pragma unroll
    for (int i = 0; i < 4; i++) {
        const int e = base + i * 256 + threadIdx.x;
        if (e < E) {
            const int vn = nidx[e], ve = eidx[e];
            const int rk = rank[e];
            if (vn >= lo && vn < hi)
                srcidx[off[vn] + (rk & 0xffff)] = ve;
            if (ve >= lo && ve < hi)
                srcidx[off[N + ve] + (rk >> 16)] = vn;
        }
    }
}

__global__ __launch_bounds__(256) void invert_deg_int(const int* __restrict__ deg,
                                                      float* __restrict__ inv, int n) {
    int t = blockIdx.x * 256 + threadIdx.x;
    if (t < n) {
        const int v = deg[t];
        inv[t] = (v > 0) ? 1.0f / (float)v : 0.f;
    }
}

// ---------------------------------------------------------------------------
// CSR gather, D=128: 16 lanes per row, 2 float4 chunks per lane (cols c, c+64).
// 16 rows/block. 4-source unroll -> 8 independent VMEM loads per lane.
// ---------------------------------------------------------------------------
__global__ __launch_bounds__(256) void gather_rows_128(const float* __restrict__ src,
                                                       const int* __restrict__ off,
                                                       const int* __restrict__ srcidx,
                                                       const float* __restrict__ scale,
                                                       float* __restrict__ dst, int Nn) {
    const int row = blockIdx.x * 16 + (threadIdx.x >> 4);
    if (row >= Nn) return;
    const int c = (threadIdx.x & 15) << 2;
    const int j0 = off[row], j1 = off[row + 1];
    float4 pa = make_float4(0.f, 0.f, 0.f, 0.f);
    float4 pb = make_float4(0.f, 0.f, 0.f, 0.f);
    float4 qa = make_float4(0.f, 0.f, 0.f, 0.f);
    float4 qb = make_float4(0.f, 0.f, 0.f, 0.f);
    int j = j0;
    for (; j + 3 < j1; j += 4) {
        const int s0 = srcidx[j + 0];
        const int s1 = srcidx[j + 1];
        const int s2 = srcidx[j + 2];
        const int s3 = srcidx[j + 3];
        const float4 v0a = *(const float4*)&src[(size_t)s0 * 128 + c];
        const float4 v0b = *(const float4*)&src[(size_t)s0 * 128 + c + 64];
        const float4 v1a = *(const float4*)&src[(size_t)s1 * 128 + c];
        const float4 v1b = *(const float4*)&src[(size_t)s1 * 128 + c + 64];
        const float4 v2a = *(const float4*)&src[(size_t)s2 * 128 + c];
        const float4 v2b = *(const float4*)&src[(size_t)s2 * 128 + c + 64];
        const float4 v3a = *(const float4*)&src[(size_t)s3 * 128 + c];
        const float4 v3b = *(const float4*)&src[(size_t)s3 * 128 + c + 64];
        pa.x += v0a.x + v1a.x; pa.y += v0a.y + v1a.y;
        pa.z += v0a.z + v1a.z; pa.w += v0a.w + v1a.w;
        qa.x += v2a.x + v3a.x; qa.y += v2a.y + v3a.y;
        qa.z += v2a.z + v3a.z; qa.w += v2a.w + v3a.w;
        pb.x += v0b.x + v1b.x; pb.y += v0b.y + v1b.y;
        pb.z += v0b.z + v1b.z; pb.w += v0b.w + v1b.w;
        qb.x += v2b.x + v3b.x; qb.y += v2b.y + v3b.y;
        qb.z += v2b.z + v3b.z; qb.w += v2b.w + v3b.w;
    }
    for (; j < j1; j++) {
        const int s0 = srcidx[j];
        const float4 va = *(const float4*)&src[(size_t)s0 * 128 + c];
        const float4 vb = *(const float4*)&src[(size_t)s0 * 128 + c + 64];
        pa.x += va.x; pa.y += va.y; pa.z += va.z; pa.w += va.w;
        pb.x += vb.x; pb.y += vb.y; pb.z += vb.z; pb.w += vb.w;
    }
    float4 aca = make_float4(pa.x + qa.x, pa.y + qa.y, pa.z + qa.z, pa.w + qa.w);
    float4 acb = make_float4(pb.x + qb.x, pb.y + qb.y, pb.z + qb.z, pb.w + qb.w);
    if (scale) {
        const float s = scale[row];
        aca.x *= s; aca.y *= s; aca.z *= s; aca.w *= s;
        acb.x *= s; acb.y *= s; acb.z *= s; acb.w *= s;
    }
    *(float4*)&dst[(size_t)row * 128 + c] = aca;
    *(float4*)&dst[(size_t)row * 128 + c + 64] = acb;
}

// ---------------------------------------------------------------------------
// CSR gather, D=64: 8 lanes per row, 2 chunks (cols c, c+32). 32 rows/block.
// Optional fused epilogue: out = relu(scale[row]*sum + post_bias[col]).
// ---------------------------------------------------------------------------
__global__ __launch_bounds__(256) void gather_rows_64(const float* __restrict__ src,
                                                      const int* __restrict__ off,
                                                      const int* __restrict__ srcidx,
                                                      const float* __restrict__ scale,
                                                      const float* __restrict__ post_bias,
                                                      float* __restrict__ dst, int Nn) {
    const int row = blockIdx.x * 32 + (threadIdx.x >> 3);
    if (row >= Nn) return;
    const int c = (threadIdx.x & 7) << 2;
    const int j0 = off[row], j1 = off[row + 1];
    float4 pa = make_float4(0.f, 0.f, 0.f, 0.f);
    float4 pb = make_float4(0.f, 0.f, 0.f, 0.f);
    float4 qa = make_float4(0.f, 0.f, 0.f, 0.f);
    float4 qb = make_float4(0.f, 0.f, 0.f, 0.f);
    int j = j0;
    for (; j + 3 < j1; j += 4) {
        const int s0 = srcidx[j + 0];
        const int s1 = srcidx[j + 1];
        const int s2 = srcidx[j + 2];
        const int s3 = srcidx[j + 3];
        const float4 v0a = *(const float4*)&src[(size_t)s0 * 64 + c];
        const float4 v0b = *(const float4*)&src[(size_t)s0 * 64 + c + 32];
        const float4 v1a = *(const float4*)&src[(size_t)s1 * 64 + c];
        const float4 v1b = *(const float4*)&src[(size_t)s1 * 64 + c + 32];
        const float4 v2a = *(const float4*)&src[(size_t)s2 * 64 + c];
        const float4 v2b = *(const float4*)&src[(size_t)s2 * 64 + c + 32];
        const float4 v3a = *(const float4*)&src[(size_t)s3 * 64 + c];
        const float4 v3b = *(const float4*)&src[(size_t)s3 * 64 + c + 32];
        pa.x += v0a.x + v1a.x; pa.y += v0a.y + v1a.y;
        pa.z += v0a.z + v1a.z; pa.w += v0a.w + v1a.w;
        qa.x += v2a.x + v3a.x; qa.y += v2a.y + v3a.y;
        qa.z += v2a.z + v3a.z; qa.w += v2a.w + v3a.w;
        pb.x += v0b.x + v1b.x; pb.y += v0b.y + v1b.y;
        pb.z += v0b.z + v1b.z; pb.w += v0b.w + v1b.w;
        qb.x += v2b.x + v3b.x; qb.y += v2b.y + v3b.y;
        qb.z += v2b.z + v3b.z; qb.w += v2b.w + v3b.w;
    }
    for (; j < j1; j++) {
        const int s0 = srcidx[j];
        const float4 va = *(const float4*)&src[(size_t)s0 * 64 + c];
        const float4 vb = *(const float4*)&src[(size_t)s0 * 64 + c + 32];
        pa.x += va.x; pa.y += va.y; pa.z += va.z; pa.w += va.w;
        pb.x += vb.x; pb.y += vb.y; pb.z += vb.z; pb.w += vb.w;
    }
    float4 aca = make_float4(pa.x + qa.x, pa.y + qa.y, pa.z + qa.z, pa.w + qa.w);
    float4 acb = make_float4(pb.x + qb.x, pb.y + qb.y, pb.z + qb.z, pb.w + qb.w);
    if (scale) {
        const float s = scale[row];
        aca.x *= s; aca.y *= s; aca.z *= s; aca.w *= s;
        acb.x *= s; acb.y *= s; acb.z *= s; acb.w *= s;
    }
    if (post_bias) {
        aca.x = fmaxf(aca.x + post_bias[c + 0], 0.f);
        aca.y = fmaxf(aca.y + post_bias[c + 1], 0.f);
        aca.z = fmaxf(aca.z + post_bias[c + 2], 0.f);
        aca.w = fmaxf(aca.w + post_bias[c + 3], 0.f);
        acb.x = fmaxf(acb.x + post_bias[c + 32], 0.f);
        acb.y = fmaxf(acb.y + post_bias[c + 33], 0.f);
        acb.z = fmaxf(acb.z + post_bias[c + 34], 0.f);
        acb.w = fmaxf(acb.w + post_bias[c + 35], 0.f);
    }
    *(float4*)&dst[(size_t)row * 64 + c] = aca;
    *(float4*)&dst[(size_t)row * 64 + c + 32] = acb;
}

// ---------------------------------------------------------------------------
// GEMM1: C[M,256] = relu(dinv[row] * (A[M,128] @ B[128,256]) + bias[col])
// 128x128 tile, BK=32, split-half micro-tile.
// ---------------------------------------------------------------------------
__global__ __launch_bounds__(256) void gemm1_f32(const float* __restrict__ A,
                                                 const float* __restrict__ B,
                                                 float* __restrict__ C, int M,
                                                 const float* __restrict__ dinv,
                                                 const float* __restrict__ bias) {
    __shared__ float As[32][132];   // [k][m]
    __shared__ float Bs[32][128];   // [k][n]
    const int tid = threadIdx.x;
    const int m0 = blockIdx.y * 128;
    const int bn = blockIdx.x * 128;
    const int rq = (tid >> 4) << 2;
    const int cq = (tid & 15) << 2;

    float acc[8][8] = {{0.f}};

    for (int k0 = 0; k0 < 128; k0 += 32) {
#pragma unroll
        for (int i = 0; i < 4; i++) {
            const int f = tid + 256 * i;
            const int r = f >> 3;
            const int q = (f & 7) << 2;
            const int grow = m0 + r;
            float4 v = make_float4(0.f, 0.f, 0.f, 0.f);
            if (grow < M) v = *(const float4*)&A[(size_t)grow * 128 + k0 + q];
            As[q + 0][r] = v.x;
            As[q + 1][r] = v.y;
            As[q + 2][r] = v.z;
            As[q + 3][r] = v.w;
        }
#pragma unroll
        for (int i = 0; i < 4; i++) {
            const int f = tid + 256 * i;
            const int r = f >> 5;
            const int c4 = (f & 31) << 2;
            *(float4*)&Bs[r][c4] = *(const float4*)&B[(size_t)(k0 + r) * 256 + bn + c4];
        }
        __syncthreads();
#pragma unroll
        for (int k = 0; k < 32; k++) {
            float av[8], bv[8];
            *(float4*)&av[0] = *(const float4*)&As[k][rq];
            *(float4*)&av[4] = *(const float4*)&As[k][rq + 64];
            *(float4*)&bv[0] = *(const float4*)&Bs[k][cq];
            *(float4*)&bv[4] = *(const float4*)&Bs[k][cq + 64];
#pragma unroll
            for (int r = 0; r < 8; r++)
#pragma unroll
                for (int c = 0; c < 8; c++)
                    acc[r][c] = fmaf(av[r], bv[c], acc[r][c]);
        }
        __syncthreads();
    }
#pragma unroll
    for (int r = 0; r < 8; r++) {
        const int grow = m0 + rq + (r & 3) + ((r >> 2) << 6);
        if (grow < M) {
            const float s = dinv[grow];
            float o[8];
#pragma unroll
            for (int c = 0; c < 4; c++)
                o[c] = fmaxf(fmaf(acc[r][c], s, bias[bn + cq + c]), 0.f);
#pragma unroll
            for (int c = 4; c < 8; c++)
                o[c] = fmaxf(fmaf(acc[r][c], s, bias[bn + 64 + cq + (c - 4)]), 0.f);
            *(float4*)&C[(size_t)grow * 256 + bn + cq] = *(float4*)&o[0];
            *(float4*)&C[(size_t)grow * 256 + bn + 64 + cq] = *(float4*)&o[4];
        }
    }
}

// ---------------------------------------------------------------------------
// GEMM2: C[M,64] = A[M,256] @ B[256,64]
// ---------------------------------------------------------------------------
__global__ __launch_bounds__(256) void gemm2_f32(const float* __restrict__ A,
                                                 const float* __restrict__ B,
                                                 float* __restrict__ C, int M) {
    __shared__ float As[32][132];
    __shared__ float Bs[32][64];
    const int tid = threadIdx.x;
    const int m0 = blockIdx.y * 128;
    const int tr = (tid >> 3) << 2;
    const int tc = (tid & 7) << 3;

    float acc[4][8] = {{0.f}};

    for (int k0 = 0; k0 < 256; k0 += 32) {
#pragma unroll
        for (int i = 0; i < 4; i++) {
            const int f = tid + 256 * i;
            const int r = f >> 3;
            const int q = (f & 7) << 2;
            const int grow = m0 + r;
            float4 v = make_float4(0.f, 0.f, 0.f, 0.f);
            if (grow < M) v = *(const float4*)&A[(size_t)grow * 256 + k0 + q];
            As[q + 0][r] = v.x;
            As[q + 1][r] = v.y;
            As[q + 2][r] = v.z;
            As[q + 3][r] = v.w;
        }
#pragma unroll
        for (int i = 0; i < 2; i++) {
            const int f = tid + 256 * i;
            const int r = f >> 4;
            const int c4 = (f & 15) << 2;
            *(float4*)&Bs[r][c4] = *(const float4*)&B[(size_t)(k0 + r) * 64 + c4];
        }
        __syncthreads();
#pragma unroll
        for (int k = 0; k < 32; k++) {
            float av[4], bv[8];
            *(float4*)&av[0] = *(const float4*)&As[k][tr];
            *(float4*)&bv[0] = *(const float4*)&Bs[k][tc];
            *(float4*)&bv[4] = *(const float4*)&Bs[k][tc + 4];
#pragma unroll
            for (int r = 0; r < 4; r++)
#pragma unroll
                for (int c = 0; c < 8; c++)
                    acc[r][c] = fmaf(av[r], bv[c], acc[r][c]);
        }
        __syncthreads();
    }
#pragma unroll
    for (int r = 0; r < 4; r++) {
        const int grow = m0 + tr + r;
        if (grow < M) {
            *(float4*)&C[(size_t)grow * 64 + tc] =
                make_float4(acc[r][0], acc[r][1], acc[r][2], acc[r][3]);
            *(float4*)&C[(size_t)grow * 64 + tc + 4] =
                make_float4(acc[r][4], acc[r][5], acc[r][6], acc[r][7]);
        }
    }
}

// ---------------------------------------------------------------------------
// hyperedge embedding: preload all 16 indices, 16 independent guarded gathers.
// ---------------------------------------------------------------------------
__global__ __launch_bounds__(256) void hye_emb_kernel(const float* __restrict__ emb,
                                                      const int* __restrict__ hnode,
                                                      const float* __restrict__ hlen,
                                                      float* __restrict__ out, int Nn) {
    const int r = blockIdx.x * 16 + (threadIdx.x >> 4);
    const int c = (threadIdx.x & 15) << 2;
    if (r >= Nn) return;
    const int4* hp4 = (const int4*)&hnode[(size_t)r * 16];
    const int4 w0 = hp4[0], w1 = hp4[1], w2 = hp4[2], w3 = hp4[3];
    int idx[16] = {w0.x, w0.y, w0.z, w0.w, w1.x, w1.y, w1.z, w1.w,
                   w2.x, w2.y, w2.z, w2.w, w3.x, w3.y, w3.z, w3.w};
    float4 a0 = make_float4(0.f, 0.f, 0.f, 0.f);
    float4 a1 = make_float4(0.f, 0.f, 0.f, 0.f);
    float4 a2 = make_float4(0.f, 0.f, 0.f, 0.f);
    float4 a3 = make_float4(0.f, 0.f, 0.f, 0.f);
#pragma unroll
    for (int l = 0; l < 16; l += 4) {
        if (idx[l + 0] > 0) {
            const float4 v = *(const float4*)&emb[(size_t)(idx[l + 0] - 1) * 64 + c];
            a0.x += v.x; a0.y += v.y; a0.z += v.z; a0.w += v.w;
        }
        if (idx[l + 1] > 0) {
            const float4 v = *(const float4*)&emb[(size_t)(idx[l + 1] - 1) * 64 + c];
            a1.x += v.x; a1.y += v.y; a1.z += v.z; a1.w += v.w;
        }
        if (idx[l + 2] > 0) {
            const float4 v = *(const float4*)&emb[(size_t)(idx[l + 2] - 1) * 64 + c];
            a2.x += v.x; a2.y += v.y; a2.z += v.z; a2.w += v.w;
        }
        if (idx[l + 3] > 0) {
            const float4 v = *(const float4*)&emb[(size_t)(idx[l + 3] - 1) * 64 + c];
            a3.x += v.x; a3.y += v.y; a3.z += v.z; a3.w += v.w;
        }
    }
    const float inv = 1.0f / (hlen[r] + 1e-15f);
    float4 acc;
    acc.x = (a0.x + a1.x + a2.x + a3.x) * inv;
    acc.y = (a0.y + a1.y + a2.y + a3.y) * inv;
    acc.z = (a0.z + a1.z + a2.z + a3.z) * inv;
    acc.w = (a0.w + a1.w + a2.w + a3.w) * inv;
    *(float4*)&out[(size_t)r * 64 + c] = acc;
}

// ---------------------------------------------------------------------------
// Fusion-attention scores: 64x128 tile (50KB LDS -> 3 blocks/CU), K=64,
// 4x8 split-half micro-tile, fused tanh*W2 reduce.
// grid = (cdiv(Nn,64), 8); blockIdx.y = head*4 + comp.
// ---------------------------------------------------------------------------
struct AttnArgs {
    const float* z[8];
    const float* W1c; const float* b1c; const float* W2c;
    const float* W1m; const float* b1m; const float* W2m;
    float* accw;
    int Nn;
};

__global__ __launch_bounds__(256) void attn_gemm(AttnArgs a) {
    __shared__ float As[64][68];    // [k][m], 64 rows
    __shared__ float Bs[64][128];   // [k][h]
    __shared__ float red[4];
    const int tid = threadIdx.x;
    const int gy = blockIdx.y;
    const int head = gy >> 2;
    const float* __restrict__ z  = a.z[gy];
    const float* __restrict__ W1 = head ? a.W1m : a.W1c;
    const float* __restrict__ b1 = head ? a.b1m : a.b1c;
    const float* __restrict__ W2 = head ? a.W2m : a.W2c;
    const int m0 = blockIdx.x * 64;

    // stage A transposed: thread (m = tid>>2, qbase = tid&3), 4 iters over q.
    // Store banks: ((4q+j)*68 + m) -> 2-way max (free).
    {
        const int m = tid >> 2;
        const int qb = tid & 3;
        const int grow = m0 + m;
#pragma unroll
        for (int it = 0; it < 4; it++) {
            const int q = qb + 4 * it;   // float4 col index 0..15
            float4 v = make_float4(0.f, 0.f, 0.f, 0.f);
            if (grow < a.Nn) v = *(const float4*)&z[(size_t)grow * 64 + q * 4];
            As[q * 4 + 0][m] = v.x;
            As[q * 4 + 1][m] = v.y;
            As[q * 4 + 2][m] = v.z;
            As[q * 4 + 3][m] = v.w;
        }
    }
    // stage B: W1 [64][128]
    {
#pragma unroll
        for (int i = 0; i < 8; i++) {
            const int f = tid + 256 * i;
            const int r = f >> 5, cc = (f & 31) << 2;
            *(float4*)&Bs[r][cc] = *(const float4*)&W1[(size_t)r * 128 + cc];
        }
    }
    __syncthreads();

    const int mq = (tid & 15) << 2;   // rows mq..mq+3
    const int cq = (tid >> 4) << 2;   // cols cq..cq+3 and cq+64..cq+67
    float acc[4][8] = {{0.f}};
    for (int k = 0; k < 64; k++) {
        float av[4], bv[8];
        *(float4*)&av[0] = *(const float4*)&As[k][mq];
        *(float4*)&bv[0] = *(const float4*)&Bs[k][cq];
        *(float4*)&bv[4] = *(const float4*)&Bs[k][cq + 64];
#pragma unroll
        for (int r = 0; r < 4; r++)
#pragma unroll
            for (int c = 0; c < 8; c++)
                acc[r][c] = fmaf(av[r], bv[c], acc[r][c]);
    }

    float w2v[8], b1v[8];
#pragma unroll
    for (int c = 0; c < 8; c++) {
        const int col = cq + (c & 3) + ((c >> 2) << 6);
        w2v[c] = W2[col];
        b1v[c] = b1[col];
    }
    float local = 0.f;
#pragma unroll
    for (int r = 0; r < 4; r++) {
        if (m0 + mq + r < a.Nn) {
#pragma unroll
            for (int c = 0; c < 8; c++) {
                float s = acc[r][c] + b1v[c];
                s = fminf(fmaxf(s, -15.f), 15.f);
                const float t = __expf(2.f * s);
                local += (1.f - 2.f / (t + 1.f)) * w2v[c];
            }
        }
    }
#pragma unroll
    for (int off = 32; off >= 1; off >>= 1) local += __shfl_down(local, off, 64);
    if ((tid & 63) == 0) red[tid >> 6] = local;
    __syncthreads();
    if (tid == 0) atomicAdd(&a.accw[gy], red[0] + red[1] + red[2] + red[3]);
}

__global__ void softmax_beta(const float* __restrict__ acc, float* __restrict__ beta,
                             float invN) {
    const int t = threadIdx.x;
    if (t < 2) {
        const float* a = acc + 4 * t;
        float* b = beta + 4 * t;
        float w[4], m = -1e30f;
#pragma unroll
        for (int i = 0; i < 4; i++) { w[i] = a[i] * invN; m = fmaxf(m, w[i]); }
        float s = 0.f;
#pragma unroll
        for (int i = 0; i < 4; i++) { w[i] = expf(w[i] - m); s += w[i]; }
#pragma unroll
        for (int i = 0; i < 4; i++) b[i] = w[i] / s;
    }
}

__global__ __launch_bounds__(256) void weighted_sum(const float* __restrict__ z0,
                                                    const float* __restrict__ z1,
                                                    const float* __restrict__ z2,
                                                    const float* __restrict__ z3,
                                                    const float* __restrict__ beta,
                                                    float* __restrict__ out, int Nn) {
    const int t = blockIdx.x * 256 + threadIdx.x;
    if (t >= Nn * 16) return;
    const float b0 = beta[0], b1 = beta[1], b2 = beta[2], b3 = beta[3];
    const float4 v0 = *(const float4*)&z0[(size_t)t * 4];
    const float4 v1 = *(const float4*)&z1[(size_t)t * 4];
    const float4 v2 = *(const float4*)&z2[(size_t)t * 4];
    const float4 v3 = *(const float4*)&z3[(size_t)t * 4];
    float4 o;
    o.x = b0 * v0.x + b1 * v1.x + b2 * v2.x + b3 * v3.x;
    o.y = b0 * v0.y + b1 * v1.y + b2 * v2.y + b3 * v3.y;
    o.z = b0 * v0.z + b1 * v1.z + b2 * v2.z + b3 * v3.z;
    o.w = b0 * v0.w + b1 * v1.w + b2 * v2.w + b3 * v3.w;
    *(float4*)&out[(size_t)t * 4] = o;
}

// ---------------------------------------------------------------------------
extern "C" void kernel_launch(void* const* d_in, const int* in_sizes, int n_in,
                              void* d_out, int out_size, void* d_ws, size_t ws_size,
                              hipStream_t stream) {
    const int Nn = in_sizes[0] / NF;   // 50000
    const int E  = in_sizes[1] / 2;    // 800000
    const int N2 = 2 * Nn;

    const float* x[4];
    const int*   ei[4];
    const int*   hnode[4];
    const float* hlen[4];
    for (int g = 0; g < 4; g++) {
        x[g]     = (const float*)d_in[4 * g + 0];
        ei[g]    = (const int*)d_in[4 * g + 1];
        hnode[g] = (const int*)d_in[4 * g + 2];
        hlen[g]  = (const float*)d_in[4 * g + 3];
    }
    const float* W1   = (const float*)d_in[16];
    const float* b1   = (const float*)d_in[17];
    const float* W2   = (const float*)d_in[18];
    const float* b2   = (const float*)d_in[19];
    const float* acW1 = (const float*)d_in[20];
    const float* acb1 = (const float*)d_in[21];
    const float* acW2 = (const float*)d_in[22];
    const float* amW1 = (const float*)d_in[23];
    const float* amb1 = (const float*)d_in[24];
    const float* amW2 = (const float*)d_in[25];

    // workspace layout
    float* ws = (float*)d_ws;
    size_t o = 0;
    float* bufA = ws + o; o += (size_t)Nn * DD1;
    float* bufB = ws + o; o += (size_t)Nn * DD1;
    float* dinv = ws + o; o += N2;          // [d_inv(N) | b_inv(N)]
    float* h2[4];
    float* hemb[4];
    for (int g = 0; g < 4; g++) { h2[g]   = ws + o; o += (size_t)Nn * DD2; }
    for (int g = 0; g < 4; g++) { hemb[g] = ws + o; o += (size_t)Nn * DD2; }
    float* accw = ws + o; o += 8;
    float* beta = ws + o; o += 8;
    int* iws = (int*)(ws + o);
    size_t io = 0;
    int* deg_i    = iws + io; io += N2;
    int* off      = iws + io; io += N2 + 1;
    int* partials = iws + io; io += 256;
    int* rank     = iws + io; io += E;
    int* srcidx   = iws + io; io += (size_t)2 * E;

    const int nScanBlocks = cdiv(N2, 1024);
    const int shardSize = cdiv(Nn, 8);

    for (int g = 0; g < 4; g++) {
        const int* nidx = ei[g];
        const int* eidx = ei[g] + E;
        const int* off_n = off;        // CSR by nidx (edge -> node passes)
        const int* off_e = off + Nn;   // CSR by eidx (node -> edge passes)
        const float* d_inv = dinv;
        const float* b_inv = dinv + Nn;

        // ---- build CSRs ----
        hipMemsetAsync(deg_i, 0, (size_t)N2 * sizeof(int), stream);
        count_rank<<<cdiv(E, 256), 256, 0, stream>>>(nidx, eidx, deg_i, rank, Nn, E);
        scan_blocks<<<nScanBlocks, 256, 0, stream>>>(deg_i, off, partials, N2);
        scan_partials<<<1, 256, 0, stream>>>(partials, nScanBlocks);
        scan_add<<<cdiv(N2, 256), 256, 0, stream>>>(off, partials, N2, 2 * E);
        build_fill<<<8 * cdiv(E, 1024), 256, 0, stream>>>(nidx, eidx, rank, off,
                                                          srcidx, Nn, E, shardSize);
        invert_deg_int<<<cdiv(N2, 256), 256, 0, stream>>>(deg_i, dinv, N2);

        // ---- hconv1 (W1 commuted past segment-sums) ----
        gather_rows_128<<<cdiv(Nn, 16), 256, 0, stream>>>(x[g], off_e, srcidx, b_inv, bufB, Nn);
        gather_rows_128<<<cdiv(Nn, 16), 256, 0, stream>>>(bufB, off_n, srcidx, nullptr, bufA, Nn);
        gemm1_f32<<<dim3(2, cdiv(Nn, 128)), 256, 0, stream>>>(bufA, W1, bufB, Nn, d_inv, b1);

        // ---- hconv2 ----
        gemm2_f32<<<dim3(1, cdiv(Nn, 128)), 256, 0, stream>>>(bufB, W2, bufA, Nn);
        gather_rows_64<<<cdiv(Nn, 32), 256, 0, stream>>>(bufA, off_e, srcidx, b_inv,
                                                         nullptr, bufB, Nn);
        gather_rows_64<<<cdiv(Nn, 32), 256, 0, stream>>>(bufB, off_n, srcidx, d_inv,
                                                         b2, h2[g], Nn);

        // hyperedge embedding
        hye_emb_kernel<<<cdiv(Nn, 16), 256, 0, stream>>>(h2[g], hnode[g], hlen[g], hemb[g], Nn);
    }

    // ---- fusion attention ----
    hipMemsetAsync(accw, 0, 8 * sizeof(float), stream);
    AttnArgs aa;
    aa.z[0] = h2[1]; aa.z[1] = hemb[0]; aa.z[2] = h2[2]; aa.z[3] = hemb[2];
    aa.z[4] = h2[0]; aa.z[5] = hemb[1]; aa.z[6] = h2[3]; aa.z[7] = hemb[3];
    aa.W1c = acW1; aa.b1c = acb1; aa.W2c = acW2;
    aa.W1m = amW1; aa.b1m = amb1; aa.W2m = amW2;
    aa.accw = accw; aa.Nn = Nn;
    attn_gemm<<<dim3(cdiv(Nn, 64), 8), 256, 0, stream>>>(aa);
    softmax_beta<<<1, 64, 0, stream>>>(accw, beta, 1.0f / (float)Nn);

    float* out = (float*)d_out;
    weighted_sum<<<cdiv(Nn * 16, 256), 256, 0, stream>>>(h2[1], hemb[0], h2[2], hemb[2],
                                                         beta + 0, out, Nn);
    weighted_sum<<<cdiv(Nn * 16, 256), 256, 0, stream>>>(h2[0], hemb[1], h2[3], hemb[3],
                                                         beta + 4, out + (size_t)Nn * DD2, Nn);
}